// Round 1
// baseline (323.054 us; speedup 1.0000x reference)
//
#include <hip/hip_runtime.h>

// Wave-synchronous fence: DS ops complete in order within a wave (ISA
// guarantee); this only stops the COMPILER from reordering/caching LDS.
#define WAVE_SYNC() do { asm volatile("" ::: "memory"); \
                         __builtin_amdgcn_wave_barrier(); \
                         asm volatile("" ::: "memory"); } while (0)

typedef _Float16 h2 __attribute__((ext_vector_type(2)));
typedef _Float16 h4 __attribute__((ext_vector_type(4)));
typedef _Float16 h8 __attribute__((ext_vector_type(8)));

__device__ __forceinline__ float fdot2(h2 a, h2 b, float c) {
#if defined(__has_builtin)
#if __has_builtin(__builtin_amdgcn_fdot2)
    return __builtin_amdgcn_fdot2(a, b, c, false);
#else
    return (float)a[0]*(float)b[0] + (float)a[1]*(float)b[1] + c;
#endif
#else
    return (float)a[0]*(float)b[0] + (float)a[1]*(float)b[1] + c;
#endif
}

__device__ __forceinline__ float dot8h(h8 a, h8 b, float c) {
    float s = c;
    #pragma unroll
    for (int i = 0; i < 4; ++i) {
        h2 x = {a[2*i], a[2*i+1]};
        h2 y = {b[2*i], b[2*i+1]};
        s = fdot2(x, y, s);
    }
    return s;
}

__device__ __forceinline__ float dot16h(h8 a0, h8 a1, h8 b0, h8 b1, float c) {
    return dot8h(a1, b1, dot8h(a0, b0, c));
}

__device__ __forceinline__ float ln_norm16(float z, float g, float bb) {
    float s = z, q = z * z;
    #pragma unroll
    for (int off = 8; off >= 1; off >>= 1) {
        s += __shfl_xor(s, off, 16);
        q += __shfl_xor(q, off, 16);
    }
    float mean = s * 0.0625f;
    float var  = q * 0.0625f - mean * mean;
    return (z - mean) * rsqrtf(var + 1e-5f) * g + bb;
}

__device__ __forceinline__ float gelu_exact(float a) {
    float xa = fabsf(a) * 0.70710678118654752f;
    float tt = 1.f / (1.f + 0.3275911f * xa);
    float poly = tt * (0.254829592f + tt * (-0.284496736f + tt * (1.421413741f
               + tt * (-1.453152027f + tt * 1.061405429f))));
    float erfv = 1.f - poly * __expf(-xa * xa);
    erfv = a >= 0.f ? erfv : -erfv;
    return 0.5f * a * (1.f + erfv);
}

// ========================= Kernel F: conv frontend ===========================
// v2: 2 waves / sample (128 thr), grid 2048 -> 16 waves/CU (was 8, grid-capped).
// - Stage 0 (x -> LDS f16 ring) DELETED. Stage 1 reads x direct from global:
//   one time-column per lane (125 of 128 lanes), the 64 channel values live in
//   VGPRs, conv_s_w rows are wave-uniform -> wide s_loads.
// - XSP stored as f16, stride 210 halfs: 210/2=105 === 9 (mod 32), gcd(9,32)=1
//   -> 16 channel rows hit 16 distinct banks; qg groups offset by 10 banks.
//   LDS 17.9KB -> 8.5KB.
// - Stage 2: 448 (ch,slot) items over 16x8 lanes, 4 slots/lane (was 7).
#define FS_XSTR 210         // XSP row stride in halfs
#define FS_PF   1680        // float idx of pool region (= half idx 3360)
#define FS_TOTF 2128        // 8512 B total LDS

extern "C" __global__ __launch_bounds__(128, 4)
void eegnet_frontend(
    const float* __restrict__ x,
    const float* __restrict__ conv_t_w, const float* __restrict__ conv_t_b,
    const float* __restrict__ bn1_g, const float* __restrict__ bn1_b,
    const float* __restrict__ bn1_m, const float* __restrict__ bn1_v,
    const float* __restrict__ conv_s_w, const float* __restrict__ conv_s_b,
    const float* __restrict__ bn2_g, const float* __restrict__ bn2_b,
    const float* __restrict__ bn2_m, const float* __restrict__ bn2_v,
    const float* __restrict__ proj_w, const float* __restrict__ proj_b,
    float* __restrict__ tokws)
{
    __shared__ __align__(16) float sm[FS_TOTF];
    _Float16* smh = reinterpret_cast<_Float16*>(sm);
    const int b   = blockIdx.x;
    const int tid = threadIdx.x;

    // ---- zero the pad zones of XSP: per row [0,32) and [157,210) ----
    for (int i = tid; i < 16 * 85; i += 128) {
        int row = i / 85, k = i - row * 85;
        int off = (k < 32) ? k : (k + 125);
        smh[row * FS_XSTR + off] = (_Float16)0.f;
    }

    // ---- stage 1: spatial conv direct from global; one time-column/lane ----
    if (tid < 125) {
        const float* xb = x + (size_t)b * 8000 + tid;
        float xc[64];
        #pragma unroll
        for (int c = 0; c < 64; ++c) xc[c] = xb[c * 125];   // coalesced dwords
        #pragma unroll
        for (int o = 0; o < 16; ++o) {
            const float* wr = conv_s_w + o * 64;            // uniform -> s_load
            float acc = 0.f;
            #pragma unroll
            for (int c = 0; c < 64; ++c) acc += wr[c] * xc[c];
            smh[o * FS_XSTR + 32 + tid] = (_Float16)acc;    // consecutive halfs
        }
    }

    __syncthreads();   // XSP (both waves) ready

    // ---- fused BN constants + temporal taps ----
    const int oo = tid & 15, qg = tid >> 4, gg = oo >> 1;
    float sa, cc;
    {
        float s1 = bn1_g[gg] * rsqrtf(bn1_v[gg] + 1e-5f);
        float b1 = (conv_t_b[gg] - bn1_m[gg]) * s1 + bn1_b[gg];
        float s2 = bn2_g[oo] * rsqrtf(bn2_v[oo] + 1e-5f);
        float ssum = 0.f;
        const float4* csw = reinterpret_cast<const float4*>(conv_s_w + oo * 64);
        #pragma unroll
        for (int i = 0; i < 16; ++i) {
            float4 v = csw[i];
            ssum += v.x + v.y + v.z + v.w;
        }
        sa = s1 * s2;
        cc = (b1 * ssum + conv_s_b[oo] - bn2_m[oo]) * s2 + bn2_b[oo];
    }
    float wt[63];
    #pragma unroll
    for (int k = 0; k < 63; ++k) wt[k] = conv_t_w[gg * 63 + k];

    // ---- stage 2: temporal conv + BN + ELU + avg-pool (4 slots/lane) ----
    #pragma unroll 2
    for (int jj = 0; jj < 4; ++jj) {
        int j  = qg * 4 + jj;            // 0..31, slots 25..31 are clamped dups
        int jc = min(j, 24);
        int base = oo * FS_XSTR + 5 * jc + 1;
        float acc5[5] = {0.f, 0.f, 0.f, 0.f, 0.f};
        #pragma unroll
        for (int m = 0; m < 67; ++m) {
            float xv = (float)smh[base + m];
            #pragma unroll
            for (int u = 0; u < 5; ++u)
                if (u <= m && m - u <= 62) acc5[u] += wt[m - u] * xv;
        }
        float psum = 0.f;
        #pragma unroll
        for (int u = 0; u < 5; ++u) {
            float v = acc5[u] * sa + cc;
            psum += (v > 0.f) ? v : (__expf(v) - 1.f);
        }
        if (j == jc) sm[FS_PF + oo * 28 + j] = psum * 0.2f;
    }

    __syncthreads();   // pooled values ready

    // ---- stage 3: token projection -> global TOK ----
    if (tid < 80) {
        int p = tid >> 4, dd = tid & 15;
        float acc = proj_b[dd];
        const float4* wp = reinterpret_cast<const float4*>(proj_w + dd * 80);
        #pragma unroll
        for (int i = 0; i < 20; ++i) {
            float4 w4 = wp[i];
            acc += w4.x * sm[FS_PF + ((4*i+0)/5) * 28 + p * 5 + ((4*i+0)%5)];
            acc += w4.y * sm[FS_PF + ((4*i+1)/5) * 28 + p * 5 + ((4*i+1)%5)];
            acc += w4.z * sm[FS_PF + ((4*i+2)/5) * 28 + p * 5 + ((4*i+2)%5)];
            acc += w4.w * sm[FS_PF + ((4*i+3)/5) * 28 + p * 5 + ((4*i+3)%5)];
        }
        tokws[b * 80 + p * 16 + dd] = acc;
    }
}

// ===================== Kernel T: transformer + head (f16 operands) ===========
// Unchanged this round (passed, absmax 3.9e-3). Next target: grid-limited
// occupancy (512 blocks = 2 blocks/CU).
#define WQKVH 0          // 192 rows, stride 24 halfs
#define WOUTH 4608       // 16 rows, stride 72
#define WM1H  5760       // 32 rows, stride 24
#define WM2H  6528       // 16 rows, stride 40
#define BQKVF 3584       // float idx
#define BOUTF 3776
#define BM1F  3792
#define BM2F  3824
#define LN1GF 3840
#define LN1BF 3856
#define LN2GF 3872
#define LN2BF 3888
#define SCR0  7808       // half idx
#define SSTRH 1584
#define SH1H  0
#define SQKVH 144
#define SMHSH 1344
#define T_BYTES 28288

extern "C" __global__ __launch_bounds__(256, 2)
void eegnet_transformer(
    const float* __restrict__ cls_token, const float* __restrict__ pe,
    const float* __restrict__ qkv_w, const float* __restrict__ qkv_b,
    const float* __restrict__ out_w, const float* __restrict__ out_b,
    const float* __restrict__ ln1_g, const float* __restrict__ ln1_b,
    const float* __restrict__ ln2_g, const float* __restrict__ ln2_b,
    const float* __restrict__ mlp_w1, const float* __restrict__ mlp_b1,
    const float* __restrict__ mlp_w2, const float* __restrict__ mlp_b2,
    const float* __restrict__ head_ln_g, const float* __restrict__ head_ln_b,
    const float* __restrict__ head_w, const float* __restrict__ head_b,
    const float* __restrict__ tokws, float* __restrict__ out)
{
    __shared__ __align__(16) unsigned char smb[T_BYTES];
    float*    smf = reinterpret_cast<float*>(smb);
    _Float16* smh = reinterpret_cast<_Float16*>(smb);

    const int tid = threadIdx.x;
    const int ss  = tid >> 7;
    const int u   = tid & 127;
    const int sA  = blockIdx.x * 4 + ss * 2;
    const int d16 = u & 15, qg = u >> 4;
    const int t6c = min(qg, 5);
    const int wav = u >> 6, al = u & 63;
    const int sbA = SCR0 + (ss * 2    ) * SSTRH;
    const int sbB = SCR0 + (ss * 2 + 1) * SSTRH;

    float zA, zB;
    {
        float peV = pe[t6c * 16 + d16];
        if (t6c == 0) {
            float cv = cls_token[d16];
            zA = cv + peV; zB = cv + peV;
        } else {
            zA = tokws[(sA    ) * 80 + (t6c - 1) * 16 + d16] + peV;
            zB = tokws[(sA + 1) * 80 + (t6c - 1) * 16 + d16] + peV;
        }
    }

    #pragma unroll 1
    for (int li = 0; li < 6; ++li) {
        __syncthreads();

        {
            const float4* s1 = reinterpret_cast<const float4*>(qkv_w + li * 3072);
            #pragma unroll
            for (int it = 0; it < 3; ++it) {
                int i = tid + it * 256;
                float4 v = s1[i];
                int j = i >> 2, k = (i & 3) << 2;
                h4 hv = {(_Float16)v.x, (_Float16)v.y, (_Float16)v.z, (_Float16)v.w};
                *reinterpret_cast<h4*>(&smh[WQKVH + j * 24 + k]) = hv;
            }
            {
                float4 v = reinterpret_cast<const float4*>(out_w + li * 1024)[tid];
                int j = tid >> 4, k = (tid & 15) << 2;
                h4 hv = {(_Float16)v.x, (_Float16)v.y, (_Float16)v.z, (_Float16)v.w};
                *reinterpret_cast<h4*>(&smh[WOUTH + j * 72 + k]) = hv;
            }
            if (tid < 128) {
                float4 v = reinterpret_cast<const float4*>(mlp_w1 + li * 512)[tid];
                int j = tid >> 2, k = (tid & 3) << 2;
                h4 hv = {(_Float16)v.x, (_Float16)v.y, (_Float16)v.z, (_Float16)v.w};
                *reinterpret_cast<h4*>(&smh[WM1H + j * 24 + k]) = hv;
            } else {
                int i = tid - 128;
                float4 v = reinterpret_cast<const float4*>(mlp_w2 + li * 512)[i];
                int j = i >> 3, k = (i & 7) << 2;
                h4 hv = {(_Float16)v.x, (_Float16)v.y, (_Float16)v.z, (_Float16)v.w};
                *reinterpret_cast<h4*>(&smh[WM2H + j * 40 + k]) = hv;
            }
            if (tid < 192) smf[BQKVF + tid] = qkv_b[li * 192 + tid];
            else if (tid < 208) smf[BOUTF + tid - 192] = out_b[li * 16 + tid - 192];
            else if (tid < 240) smf[BM1F + tid - 208]  = mlp_b1[li * 32 + tid - 208];
            else               smf[BM2F + tid - 240]  = mlp_b2[li * 16 + tid - 240];
            if (tid >= 64 && tid < 80)        smf[LN1GF + tid - 64]  = ln1_g[li * 16 + tid - 64];
            else if (tid >= 80 && tid < 96)   smf[LN1BF + tid - 80]  = ln1_b[li * 16 + tid - 80];
            else if (tid >= 96 && tid < 112)  smf[LN2GF + tid - 96]  = ln2_g[li * 16 + tid - 96];
            else if (tid >= 112 && tid < 128) smf[LN2BF + tid - 112] = ln2_b[li * 16 + tid - 112];
        }
        __syncthreads();

        {
            float g = smf[LN1GF + d16], bb = smf[LN1BF + d16];
            smh[sbA + SH1H + t6c * 24 + d16] = (_Float16)ln_norm16(zA, g, bb);
            smh[sbB + SH1H + t6c * 24 + d16] = (_Float16)ln_norm16(zB, g, bb);
        }
        WAVE_SYNC();

        h8 hA0 = *reinterpret_cast<const h8*>(&smh[sbA + SH1H + t6c * 24]);
        h8 hA1 = *reinterpret_cast<const h8*>(&smh[sbA + SH1H + t6c * 24 + 8]);
        h8 hB0 = *reinterpret_cast<const h8*>(&smh[sbB + SH1H + t6c * 24]);
        h8 hB1 = *reinterpret_cast<const h8*>(&smh[sbB + SH1H + t6c * 24 + 8]);

        #pragma unroll 2
        for (int r = 0; r < 12; ++r) {
            int j = d16 + 16 * r;
            h8 w0 = *reinterpret_cast<const h8*>(&smh[WQKVH + j * 24]);
            h8 w1 = *reinterpret_cast<const h8*>(&smh[WQKVH + j * 24 + 8]);
            float bb = smf[BQKVF + j];
            smh[sbA + SQKVH + t6c * 200 + j] = (_Float16)dot16h(hA0, hA1, w0, w1, bb);
            smh[sbB + SQKVH + t6c * 200 + j] = (_Float16)dot16h(hB0, hB1, w0, w1, bb);
        }
        __syncthreads();

        {
            bool act = (wav == 0) ? (al < 32) : (al < 16);
            if (act) {
                int h  = al & 7;
                int qs = (wav == 0) ? (al >> 3) : 4 + (al >> 3);
                const int qoffA = sbA + SQKVH + qs * 200 + h * 8;
                const int qoffB = sbB + SQKVH + qs * 200 + h * 8;
                h8 qA = *reinterpret_cast<const h8*>(&smh[qoffA]);
                h8 qB = *reinterpret_cast<const h8*>(&smh[qoffB]);
                float scA[6], scB[6];
                #pragma unroll
                for (int t = 0; t < 6; ++t) {
                    h8 kA = *reinterpret_cast<const h8*>(&smh[sbA + SQKVH + t * 200 + 64 + h * 8]);
                    h8 kB = *reinterpret_cast<const h8*>(&smh[sbB + SQKVH + t * 200 + 64 + h * 8]);
                    scA[t] = dot8h(qA, kA, 0.f) * 0.35355339059327373f;
                    scB[t] = dot8h(qB, kB, 0.f) * 0.35355339059327373f;
                }
                float mxA = scA[0], mxB = scB[0];
                #pragma unroll
                for (int t = 1; t < 6; ++t) { mxA = fmaxf(mxA, scA[t]); mxB = fmaxf(mxB, scB[t]); }
                float suA = 0.f, suB = 0.f;
                #pragma unroll
                for (int t = 0; t < 6; ++t) {
                    scA[t] = __expf(scA[t] - mxA); suA += scA[t];
                    scB[t] = __expf(scB[t] - mxB); suB += scB[t];
                }
                float ivA = 1.f / suA, ivB = 1.f / suB;
                h2 oA[4], oB[4];
                #pragma unroll
                for (int k2 = 0; k2 < 4; ++k2) { oA[k2] = h2{0, 0}; oB[k2] = h2{0, 0}; }
                #pragma unroll
                for (int t = 0; t < 6; ++t) {
                    h8 vA = *reinterpret_cast<const h8*>(&smh[sbA + SQKVH + t * 200 + 128 + h * 8]);
                    h8 vB = *reinterpret_cast<const h8*>(&smh[sbB + SQKVH + t * 200 + 128 + h * 8]);
                    _Float16 aa = (_Float16)(scA[t] * ivA);
                    _Float16 ab = (_Float16)(scB[t] * ivB);
                    h2 av = {aa, aa}, bv = {ab, ab};
                    #pragma unroll
                    for (int k2 = 0; k2 < 4; ++k2) {
                        h2 va = {vA[2*k2], vA[2*k2+1]};
                        h2 vb = {vB[2*k2], vB[2*k2+1]};
                        oA[k2] += av * va;
                        oB[k2] += bv * vb;
                    }
                }
                h8 stA, stB;
                #pragma unroll
                for (int k2 = 0; k2 < 4; ++k2) {
                    stA[2*k2] = oA[k2][0]; stA[2*k2+1] = oA[k2][1];
                    stB[2*k2] = oB[k2][0]; stB[2*k2+1] = oB[k2][1];
                }
                *reinterpret_cast<h8*>(&smh[qoffA]) = stA;
                *reinterpret_cast<h8*>(&smh[qoffB]) = stB;
            }
        }
        WAVE_SYNC();

        {
            float aA = smf[BOUTF + d16], aB = aA;
            #pragma unroll
            for (int i = 0; i < 8; ++i) {
                h8 w  = *reinterpret_cast<const h8*>(&smh[WOUTH + d16 * 72 + 8 * i]);
                h8 va = *reinterpret_cast<const h8*>(&smh[sbA + SQKVH + t6c * 200 + 8 * i]);
                h8 vb = *reinterpret_cast<const h8*>(&smh[sbB + SQKVH + t6c * 200 + 8 * i]);
                aA = dot8h(va, w, aA);
                aB = dot8h(vb, w, aB);
            }
            zA += aA; zB += aB;
        }

        {
            float g = smf[LN2GF + d16], bb = smf[LN2BF + d16];
            smh[sbA + SH1H + t6c * 24 + d16] = (_Float16)ln_norm16(zA, g, bb);
            smh[sbB + SH1H + t6c * 24 + d16] = (_Float16)ln_norm16(zB, g, bb);
        }
        WAVE_SYNC();
        hA0 = *reinterpret_cast<const h8*>(&smh[sbA + SH1H + t6c * 24]);
        hA1 = *reinterpret_cast<const h8*>(&smh[sbA + SH1H + t6c * 24 + 8]);
        hB0 = *reinterpret_cast<const h8*>(&smh[sbB + SH1H + t6c * 24]);
        hB1 = *reinterpret_cast<const h8*>(&smh[sbB + SH1H + t6c * 24 + 8]);

        #pragma unroll
        for (int r = 0; r < 2; ++r) {
            int uu = d16 + 16 * r;
            h8 w0 = *reinterpret_cast<const h8*>(&smh[WM1H + uu * 24]);
            h8 w1 = *reinterpret_cast<const h8*>(&smh[WM1H + uu * 24 + 8]);
            float bb = smf[BM1F + uu];
            float aA = dot16h(hA0, hA1, w0, w1, bb);
            float aB = dot16h(hB0, hB1, w0, w1, bb);
            smh[sbA + SMHSH + t6c * 40 + uu] = (_Float16)gelu_exact(aA);
            smh[sbB + SMHSH + t6c * 40 + uu] = (_Float16)gelu_exact(aB);
        }
        WAVE_SYNC();

        {
            float aA = smf[BM2F + d16], aB = aA;
            #pragma unroll
            for (int i = 0; i < 4; ++i) {
                h8 w  = *reinterpret_cast<const h8*>(&smh[WM2H + d16 * 40 + 8 * i]);
                h8 va = *reinterpret_cast<const h8*>(&smh[sbA + SMHSH + t6c * 40 + 8 * i]);
                h8 vb = *reinterpret_cast<const h8*>(&smh[sbB + SMHSH + t6c * 40 + 8 * i]);
                aA = dot8h(va, w, aA);
                aB = dot8h(vb, w, aB);
            }
            zA += aA; zB += aB;
        }
    }

    if (u < 16) {
        float g = head_ln_g[d16], bb = head_ln_b[d16];
        float w0 = head_w[d16], w1 = head_w[16 + d16];
        float cvA = ln_norm16(zA, g, bb);
        float cvB = ln_norm16(zB, g, bb);
        float pA0 = cvA * w0, pA1 = cvA * w1;
        float pB0 = cvB * w0, pB1 = cvB * w1;
        #pragma unroll
        for (int off = 8; off >= 1; off >>= 1) {
            pA0 += __shfl_xor(pA0, off, 16);
            pA1 += __shfl_xor(pA1, off, 16);
            pB0 += __shfl_xor(pB0, off, 16);
            pB1 += __shfl_xor(pB1, off, 16);
        }
        if (u == 0) {
            float hb0 = head_b[0], hb1 = head_b[1];
            {
                float l0 = pA0 + hb0, l1 = pA1 + hb1;
                float mx = fmaxf(l0, l1);
                float e0 = __expf(l0 - mx), e1 = __expf(l1 - mx);
                float inv = 1.f / (e0 + e1);
                out[sA * 2 + 0] = e0 * inv;
                out[sA * 2 + 1] = e1 * inv;
            }
            {
                float l0 = pB0 + hb0, l1 = pB1 + hb1;
                float mx = fmaxf(l0, l1);
                float e0 = __expf(l0 - mx), e1 = __expf(l1 - mx);
                float inv = 1.f / (e0 + e1);
                out[(sA + 1) * 2 + 0] = e0 * inv;
                out[(sA + 1) * 2 + 1] = e1 * inv;
            }
        }
    }
}

extern "C" void kernel_launch(void* const* d_in, const int* in_sizes, int n_in,
                              void* d_out, int out_size, void* d_ws, size_t ws_size,
                              hipStream_t stream) {
    (void)n_in; (void)ws_size; (void)out_size;
    const float* a0  = (const float*)d_in[0];   // x
    const float* a1  = (const float*)d_in[1];   // conv_t_w
    const float* a2  = (const float*)d_in[2];   // conv_t_b
    const float* a3  = (const float*)d_in[3];   // bn1_g
    const float* a4  = (const float*)d_in[4];   // bn1_b
    const float* a5  = (const float*)d_in[5];   // bn1_m
    const float* a6  = (const float*)d_in[6];   // bn1_v
    const float* a7  = (const float*)d_in[7];   // conv_s_w
    const float* a8  = (const float*)d_in[8];   // conv_s_b
    const float* a9  = (const float*)d_in[9];   // bn2_g
    const float* a10 = (const float*)d_in[10];  // bn2_b
    const float* a11 = (const float*)d_in[11];  // bn2_m
    const float* a12 = (const float*)d_in[12];  // bn2_v
    const float* a13 = (const float*)d_in[13];  // proj_w
    const float* a14 = (const float*)d_in[14];  // proj_b
    const float* a15 = (const float*)d_in[15];  // cls_token
    const float* a16 = (const float*)d_in[16];  // pe
    const float* a17 = (const float*)d_in[17];  // qkv_w
    const float* a18 = (const float*)d_in[18];  // qkv_b
    const float* a19 = (const float*)d_in[19];  // out_w
    const float* a20 = (const float*)d_in[20];  // out_b
    const float* a21 = (const float*)d_in[21];  // ln1_g
    const float* a22 = (const float*)d_in[22];  // ln1_b
    const float* a23 = (const float*)d_in[23];  // ln2_g
    const float* a24 = (const float*)d_in[24];  // ln2_b
    const float* a25 = (const float*)d_in[25];  // mlp_w1
    const float* a26 = (const float*)d_in[26];  // mlp_b1
    const float* a27 = (const float*)d_in[27];  // mlp_w2
    const float* a28 = (const float*)d_in[28];  // mlp_b2
    const float* a29 = (const float*)d_in[29];  // head_ln_g
    const float* a30 = (const float*)d_in[30];  // head_ln_b
    const float* a31 = (const float*)d_in[31];  // head_w
    const float* a32 = (const float*)d_in[32];  // head_b

    int Bn = in_sizes[0] / (64 * 125);          // 2048
    float* tokws = (float*)d_ws;                // 2048 x 80 f32 = 640 KB

    eegnet_frontend<<<Bn, 128, 0, stream>>>(
        a0, a1, a2, a3, a4, a5, a6, a7, a8, a9, a10, a11, a12, a13, a14, tokws);

    eegnet_transformer<<<Bn / 4, 256, 0, stream>>>(
        a15, a16, a17, a18, a19, a20, a21, a22, a23, a24, a25, a26, a27, a28,
        a29, a30, a31, a32, tokws, (float*)d_out);
}

// Round 2
// 319.061 us; speedup vs baseline: 1.0125x; 1.0125x over previous
//
#include <hip/hip_runtime.h>

// Wave-synchronous fence: DS ops complete in order within a wave (ISA
// guarantee); this only stops the COMPILER from reordering/caching LDS.
#define WAVE_SYNC() do { asm volatile("" ::: "memory"); \
                         __builtin_amdgcn_wave_barrier(); \
                         asm volatile("" ::: "memory"); } while (0)

typedef _Float16 h2 __attribute__((ext_vector_type(2)));
typedef _Float16 h4 __attribute__((ext_vector_type(4)));
typedef _Float16 h8 __attribute__((ext_vector_type(8)));

__device__ __forceinline__ float fdot2(h2 a, h2 b, float c) {
#if defined(__has_builtin)
#if __has_builtin(__builtin_amdgcn_fdot2)
    return __builtin_amdgcn_fdot2(a, b, c, false);
#else
    return (float)a[0]*(float)b[0] + (float)a[1]*(float)b[1] + c;
#endif
#else
    return (float)a[0]*(float)b[0] + (float)a[1]*(float)b[1] + c;
#endif
}

__device__ __forceinline__ float dot8h(h8 a, h8 b, float c) {
    float s = c;
    #pragma unroll
    for (int i = 0; i < 4; ++i) {
        h2 x = {a[2*i], a[2*i+1]};
        h2 y = {b[2*i], b[2*i+1]};
        s = fdot2(x, y, s);
    }
    return s;
}

__device__ __forceinline__ float dot16h(h8 a0, h8 a1, h8 b0, h8 b1, float c) {
    return dot8h(a1, b1, dot8h(a0, b0, c));
}

__device__ __forceinline__ float ln_norm16(float z, float g, float bb) {
    float s = z, q = z * z;
    #pragma unroll
    for (int off = 8; off >= 1; off >>= 1) {
        s += __shfl_xor(s, off, 16);
        q += __shfl_xor(q, off, 16);
    }
    float mean = s * 0.0625f;
    float var  = q * 0.0625f - mean * mean;
    return (z - mean) * rsqrtf(var + 1e-5f) * g + bb;
}

__device__ __forceinline__ float gelu_exact(float a) {
    float xa = fabsf(a) * 0.70710678118654752f;
    float tt = 1.f / (1.f + 0.3275911f * xa);
    float poly = tt * (0.254829592f + tt * (-0.284496736f + tt * (1.421413741f
               + tt * (-1.453152027f + tt * 1.061405429f))));
    float erfv = 1.f - poly * __expf(-xa * xa);
    erfv = a >= 0.f ? erfv : -erfv;
    return 0.5f * a * (1.f + erfv);
}

// ========================= Kernel F: conv frontend ===========================
// v3: fix round-1 spill catastrophe (VGPR=64 + xc[64]/wt[63] -> 168MB scratch
// writes). Stage 1 loop-swapped: stream over channels c, hold only 16 f32
// accumulators; xv loads stay coalesced (lane = time index). Peak register
// demand is now stage 2's wt[63]+acc5[5] (~100) -> fits the 128-VGPR cap of
// __launch_bounds__(128,4) with zero scratch.
// - 128 thr / sample, grid 2048 -> 16 waves/CU (grid-capped 50% occupancy).
// - XSP f16, stride 210 halfs: 105 === 9 (mod 32), gcd(9,32)=1 -> 16 channel
//   rows on 16 distinct banks. LDS 8.5 KB.
#define FS_XSTR 210         // XSP row stride in halfs
#define FS_PF   1680        // float idx of pool region (= half idx 3360)
#define FS_TOTF 2128        // 8512 B total LDS

extern "C" __global__ __launch_bounds__(128, 4)
void eegnet_frontend(
    const float* __restrict__ x,
    const float* __restrict__ conv_t_w, const float* __restrict__ conv_t_b,
    const float* __restrict__ bn1_g, const float* __restrict__ bn1_b,
    const float* __restrict__ bn1_m, const float* __restrict__ bn1_v,
    const float* __restrict__ conv_s_w, const float* __restrict__ conv_s_b,
    const float* __restrict__ bn2_g, const float* __restrict__ bn2_b,
    const float* __restrict__ bn2_m, const float* __restrict__ bn2_v,
    const float* __restrict__ proj_w, const float* __restrict__ proj_b,
    float* __restrict__ tokws)
{
    __shared__ __align__(16) float sm[FS_TOTF];
    _Float16* smh = reinterpret_cast<_Float16*>(sm);
    const int b   = blockIdx.x;
    const int tid = threadIdx.x;

    // ---- zero the pad zones of XSP: per row [0,32) and [157,210) ----
    for (int i = tid; i < 16 * 85; i += 128) {
        int row = i / 85, k = i - row * 85;
        int off = (k < 32) ? k : (k + 125);
        smh[row * FS_XSTR + off] = (_Float16)0.f;
    }

    // ---- stage 1: spatial conv direct from global; one time-column/lane ----
    // Loop order: c outer (streamed), o inner (16 accumulators). Only ~25 live
    // VGPRs; conv_s_w reads are wave-uniform -> s_loads.
    if (tid < 125) {
        const float* xb = x + (size_t)b * 8000 + tid;
        float acc[16];
        #pragma unroll
        for (int o = 0; o < 16; ++o) acc[o] = 0.f;
        #pragma unroll 8
        for (int c = 0; c < 64; ++c) {
            float xv = xb[c * 125];                      // coalesced dword
            #pragma unroll
            for (int o = 0; o < 16; ++o)
                acc[o] += conv_s_w[o * 64 + c] * xv;     // uniform -> s_load
        }
        #pragma unroll
        for (int o = 0; o < 16; ++o)
            smh[o * FS_XSTR + 32 + tid] = (_Float16)acc[o];
    }

    __syncthreads();   // XSP (both waves) ready

    // ---- fused BN constants + temporal taps ----
    const int oo = tid & 15, qg = tid >> 4, gg = oo >> 1;
    float sa, cc;
    {
        float s1 = bn1_g[gg] * rsqrtf(bn1_v[gg] + 1e-5f);
        float b1 = (conv_t_b[gg] - bn1_m[gg]) * s1 + bn1_b[gg];
        float s2 = bn2_g[oo] * rsqrtf(bn2_v[oo] + 1e-5f);
        float ssum = 0.f;
        const float4* csw = reinterpret_cast<const float4*>(conv_s_w + oo * 64);
        #pragma unroll
        for (int i = 0; i < 16; ++i) {
            float4 v = csw[i];
            ssum += v.x + v.y + v.z + v.w;
        }
        sa = s1 * s2;
        cc = (b1 * ssum + conv_s_b[oo] - bn2_m[oo]) * s2 + bn2_b[oo];
    }
    float wt[63];
    #pragma unroll
    for (int k = 0; k < 63; ++k) wt[k] = conv_t_w[gg * 63 + k];

    // ---- stage 2: temporal conv + BN + ELU + avg-pool (4 slots/lane) ----
    #pragma unroll 2
    for (int jj = 0; jj < 4; ++jj) {
        int j  = qg * 4 + jj;            // 0..31, slots 25..31 are clamped dups
        int jc = min(j, 24);
        int base = oo * FS_XSTR + 5 * jc + 1;
        float acc5[5] = {0.f, 0.f, 0.f, 0.f, 0.f};
        #pragma unroll
        for (int m = 0; m < 67; ++m) {
            float xv = (float)smh[base + m];
            #pragma unroll
            for (int u = 0; u < 5; ++u)
                if (u <= m && m - u <= 62) acc5[u] += wt[m - u] * xv;
        }
        float psum = 0.f;
        #pragma unroll
        for (int u = 0; u < 5; ++u) {
            float v = acc5[u] * sa + cc;
            psum += (v > 0.f) ? v : (__expf(v) - 1.f);
        }
        if (j == jc) sm[FS_PF + oo * 28 + j] = psum * 0.2f;
    }

    __syncthreads();   // pooled values ready

    // ---- stage 3: token projection -> global TOK ----
    if (tid < 80) {
        int p = tid >> 4, dd = tid & 15;
        float acc = proj_b[dd];
        const float4* wp = reinterpret_cast<const float4*>(proj_w + dd * 80);
        #pragma unroll
        for (int i = 0; i < 20; ++i) {
            float4 w4 = wp[i];
            acc += w4.x * sm[FS_PF + ((4*i+0)/5) * 28 + p * 5 + ((4*i+0)%5)];
            acc += w4.y * sm[FS_PF + ((4*i+1)/5) * 28 + p * 5 + ((4*i+1)%5)];
            acc += w4.z * sm[FS_PF + ((4*i+2)/5) * 28 + p * 5 + ((4*i+2)%5)];
            acc += w4.w * sm[FS_PF + ((4*i+3)/5) * 28 + p * 5 + ((4*i+3)%5)];
        }
        tokws[b * 80 + p * 16 + dd] = acc;
    }
}

// ===================== Kernel T: transformer + head (f16 operands) ===========
// Unchanged this round (passed, absmax 3.9e-3). Next target: grid-limited
// occupancy (512 blocks = 2 blocks/CU).
#define WQKVH 0          // 192 rows, stride 24 halfs
#define WOUTH 4608       // 16 rows, stride 72
#define WM1H  5760       // 32 rows, stride 24
#define WM2H  6528       // 16 rows, stride 40
#define BQKVF 3584       // float idx
#define BOUTF 3776
#define BM1F  3792
#define BM2F  3824
#define LN1GF 3840
#define LN1BF 3856
#define LN2GF 3872
#define LN2BF 3888
#define SCR0  7808       // half idx
#define SSTRH 1584
#define SH1H  0
#define SQKVH 144
#define SMHSH 1344
#define T_BYTES 28288

extern "C" __global__ __launch_bounds__(256, 2)
void eegnet_transformer(
    const float* __restrict__ cls_token, const float* __restrict__ pe,
    const float* __restrict__ qkv_w, const float* __restrict__ qkv_b,
    const float* __restrict__ out_w, const float* __restrict__ out_b,
    const float* __restrict__ ln1_g, const float* __restrict__ ln1_b,
    const float* __restrict__ ln2_g, const float* __restrict__ ln2_b,
    const float* __restrict__ mlp_w1, const float* __restrict__ mlp_b1,
    const float* __restrict__ mlp_w2, const float* __restrict__ mlp_b2,
    const float* __restrict__ head_ln_g, const float* __restrict__ head_ln_b,
    const float* __restrict__ head_w, const float* __restrict__ head_b,
    const float* __restrict__ tokws, float* __restrict__ out)
{
    __shared__ __align__(16) unsigned char smb[T_BYTES];
    float*    smf = reinterpret_cast<float*>(smb);
    _Float16* smh = reinterpret_cast<_Float16*>(smb);

    const int tid = threadIdx.x;
    const int ss  = tid >> 7;
    const int u   = tid & 127;
    const int sA  = blockIdx.x * 4 + ss * 2;
    const int d16 = u & 15, qg = u >> 4;
    const int t6c = min(qg, 5);
    const int wav = u >> 6, al = u & 63;
    const int sbA = SCR0 + (ss * 2    ) * SSTRH;
    const int sbB = SCR0 + (ss * 2 + 1) * SSTRH;

    float zA, zB;
    {
        float peV = pe[t6c * 16 + d16];
        if (t6c == 0) {
            float cv = cls_token[d16];
            zA = cv + peV; zB = cv + peV;
        } else {
            zA = tokws[(sA    ) * 80 + (t6c - 1) * 16 + d16] + peV;
            zB = tokws[(sA + 1) * 80 + (t6c - 1) * 16 + d16] + peV;
        }
    }

    #pragma unroll 1
    for (int li = 0; li < 6; ++li) {
        __syncthreads();

        {
            const float4* s1 = reinterpret_cast<const float4*>(qkv_w + li * 3072);
            #pragma unroll
            for (int it = 0; it < 3; ++it) {
                int i = tid + it * 256;
                float4 v = s1[i];
                int j = i >> 2, k = (i & 3) << 2;
                h4 hv = {(_Float16)v.x, (_Float16)v.y, (_Float16)v.z, (_Float16)v.w};
                *reinterpret_cast<h4*>(&smh[WQKVH + j * 24 + k]) = hv;
            }
            {
                float4 v = reinterpret_cast<const float4*>(out_w + li * 1024)[tid];
                int j = tid >> 4, k = (tid & 15) << 2;
                h4 hv = {(_Float16)v.x, (_Float16)v.y, (_Float16)v.z, (_Float16)v.w};
                *reinterpret_cast<h4*>(&smh[WOUTH + j * 72 + k]) = hv;
            }
            if (tid < 128) {
                float4 v = reinterpret_cast<const float4*>(mlp_w1 + li * 512)[tid];
                int j = tid >> 2, k = (tid & 3) << 2;
                h4 hv = {(_Float16)v.x, (_Float16)v.y, (_Float16)v.z, (_Float16)v.w};
                *reinterpret_cast<h4*>(&smh[WM1H + j * 24 + k]) = hv;
            } else {
                int i = tid - 128;
                float4 v = reinterpret_cast<const float4*>(mlp_w2 + li * 512)[i];
                int j = i >> 3, k = (i & 7) << 2;
                h4 hv = {(_Float16)v.x, (_Float16)v.y, (_Float16)v.z, (_Float16)v.w};
                *reinterpret_cast<h4*>(&smh[WM2H + j * 40 + k]) = hv;
            }
            if (tid < 192) smf[BQKVF + tid] = qkv_b[li * 192 + tid];
            else if (tid < 208) smf[BOUTF + tid - 192] = out_b[li * 16 + tid - 192];
            else if (tid < 240) smf[BM1F + tid - 208]  = mlp_b1[li * 32 + tid - 208];
            else               smf[BM2F + tid - 240]  = mlp_b2[li * 16 + tid - 240];
            if (tid >= 64 && tid < 80)        smf[LN1GF + tid - 64]  = ln1_g[li * 16 + tid - 64];
            else if (tid >= 80 && tid < 96)   smf[LN1BF + tid - 80]  = ln1_b[li * 16 + tid - 80];
            else if (tid >= 96 && tid < 112)  smf[LN2GF + tid - 96]  = ln2_g[li * 16 + tid - 96];
            else if (tid >= 112 && tid < 128) smf[LN2BF + tid - 112] = ln2_b[li * 16 + tid - 112];
        }
        __syncthreads();

        {
            float g = smf[LN1GF + d16], bb = smf[LN1BF + d16];
            smh[sbA + SH1H + t6c * 24 + d16] = (_Float16)ln_norm16(zA, g, bb);
            smh[sbB + SH1H + t6c * 24 + d16] = (_Float16)ln_norm16(zB, g, bb);
        }
        WAVE_SYNC();

        h8 hA0 = *reinterpret_cast<const h8*>(&smh[sbA + SH1H + t6c * 24]);
        h8 hA1 = *reinterpret_cast<const h8*>(&smh[sbA + SH1H + t6c * 24 + 8]);
        h8 hB0 = *reinterpret_cast<const h8*>(&smh[sbB + SH1H + t6c * 24]);
        h8 hB1 = *reinterpret_cast<const h8*>(&smh[sbB + SH1H + t6c * 24 + 8]);

        #pragma unroll 2
        for (int r = 0; r < 12; ++r) {
            int j = d16 + 16 * r;
            h8 w0 = *reinterpret_cast<const h8*>(&smh[WQKVH + j * 24]);
            h8 w1 = *reinterpret_cast<const h8*>(&smh[WQKVH + j * 24 + 8]);
            float bb = smf[BQKVF + j];
            smh[sbA + SQKVH + t6c * 200 + j] = (_Float16)dot16h(hA0, hA1, w0, w1, bb);
            smh[sbB + SQKVH + t6c * 200 + j] = (_Float16)dot16h(hB0, hB1, w0, w1, bb);
        }
        __syncthreads();

        {
            bool act = (wav == 0) ? (al < 32) : (al < 16);
            if (act) {
                int h  = al & 7;
                int qs = (wav == 0) ? (al >> 3) : 4 + (al >> 3);
                const int qoffA = sbA + SQKVH + qs * 200 + h * 8;
                const int qoffB = sbB + SQKVH + qs * 200 + h * 8;
                h8 qA = *reinterpret_cast<const h8*>(&smh[qoffA]);
                h8 qB = *reinterpret_cast<const h8*>(&smh[qoffB]);
                float scA[6], scB[6];
                #pragma unroll
                for (int t = 0; t < 6; ++t) {
                    h8 kA = *reinterpret_cast<const h8*>(&smh[sbA + SQKVH + t * 200 + 64 + h * 8]);
                    h8 kB = *reinterpret_cast<const h8*>(&smh[sbB + SQKVH + t * 200 + 64 + h * 8]);
                    scA[t] = dot8h(qA, kA, 0.f) * 0.35355339059327373f;
                    scB[t] = dot8h(qB, kB, 0.f) * 0.35355339059327373f;
                }
                float mxA = scA[0], mxB = scB[0];
                #pragma unroll
                for (int t = 1; t < 6; ++t) { mxA = fmaxf(mxA, scA[t]); mxB = fmaxf(mxB, scB[t]); }
                float suA = 0.f, suB = 0.f;
                #pragma unroll
                for (int t = 0; t < 6; ++t) {
                    scA[t] = __expf(scA[t] - mxA); suA += scA[t];
                    scB[t] = __expf(scB[t] - mxB); suB += scB[t];
                }
                float ivA = 1.f / suA, ivB = 1.f / suB;
                h2 oA[4], oB[4];
                #pragma unroll
                for (int k2 = 0; k2 < 4; ++k2) { oA[k2] = h2{0, 0}; oB[k2] = h2{0, 0}; }
                #pragma unroll
                for (int t = 0; t < 6; ++t) {
                    h8 vA = *reinterpret_cast<const h8*>(&smh[sbA + SQKVH + t * 200 + 128 + h * 8]);
                    h8 vB = *reinterpret_cast<const h8*>(&smh[sbB + SQKVH + t * 200 + 128 + h * 8]);
                    _Float16 aa = (_Float16)(scA[t] * ivA);
                    _Float16 ab = (_Float16)(scB[t] * ivB);
                    h2 av = {aa, aa}, bv = {ab, ab};
                    #pragma unroll
                    for (int k2 = 0; k2 < 4; ++k2) {
                        h2 va = {vA[2*k2], vA[2*k2+1]};
                        h2 vb = {vB[2*k2], vB[2*k2+1]};
                        oA[k2] += av * va;
                        oB[k2] += bv * vb;
                    }
                }
                h8 stA, stB;
                #pragma unroll
                for (int k2 = 0; k2 < 4; ++k2) {
                    stA[2*k2] = oA[k2][0]; stA[2*k2+1] = oA[k2][1];
                    stB[2*k2] = oB[k2][0]; stB[2*k2+1] = oB[k2][1];
                }
                *reinterpret_cast<h8*>(&smh[qoffA]) = stA;
                *reinterpret_cast<h8*>(&smh[qoffB]) = stB;
            }
        }
        WAVE_SYNC();

        {
            float aA = smf[BOUTF + d16], aB = aA;
            #pragma unroll
            for (int i = 0; i < 8; ++i) {
                h8 w  = *reinterpret_cast<const h8*>(&smh[WOUTH + d16 * 72 + 8 * i]);
                h8 va = *reinterpret_cast<const h8*>(&smh[sbA + SQKVH + t6c * 200 + 8 * i]);
                h8 vb = *reinterpret_cast<const h8*>(&smh[sbB + SQKVH + t6c * 200 + 8 * i]);
                aA = dot8h(va, w, aA);
                aB = dot8h(vb, w, aB);
            }
            zA += aA; zB += aB;
        }

        {
            float g = smf[LN2GF + d16], bb = smf[LN2BF + d16];
            smh[sbA + SH1H + t6c * 24 + d16] = (_Float16)ln_norm16(zA, g, bb);
            smh[sbB + SH1H + t6c * 24 + d16] = (_Float16)ln_norm16(zB, g, bb);
        }
        WAVE_SYNC();
        hA0 = *reinterpret_cast<const h8*>(&smh[sbA + SH1H + t6c * 24]);
        hA1 = *reinterpret_cast<const h8*>(&smh[sbA + SH1H + t6c * 24 + 8]);
        hB0 = *reinterpret_cast<const h8*>(&smh[sbB + SH1H + t6c * 24]);
        hB1 = *reinterpret_cast<const h8*>(&smh[sbB + SH1H + t6c * 24 + 8]);

        #pragma unroll
        for (int r = 0; r < 2; ++r) {
            int uu = d16 + 16 * r;
            h8 w0 = *reinterpret_cast<const h8*>(&smh[WM1H + uu * 24]);
            h8 w1 = *reinterpret_cast<const h8*>(&smh[WM1H + uu * 24 + 8]);
            float bb = smf[BM1F + uu];
            float aA = dot16h(hA0, hA1, w0, w1, bb);
            float aB = dot16h(hB0, hB1, w0, w1, bb);
            smh[sbA + SMHSH + t6c * 40 + uu] = (_Float16)gelu_exact(aA);
            smh[sbB + SMHSH + t6c * 40 + uu] = (_Float16)gelu_exact(aB);
        }
        WAVE_SYNC();

        {
            float aA = smf[BM2F + d16], aB = aA;
            #pragma unroll
            for (int i = 0; i < 4; ++i) {
                h8 w  = *reinterpret_cast<const h8*>(&smh[WM2H + d16 * 40 + 8 * i]);
                h8 va = *reinterpret_cast<const h8*>(&smh[sbA + SMHSH + t6c * 40 + 8 * i]);
                h8 vb = *reinterpret_cast<const h8*>(&smh[sbB + SMHSH + t6c * 40 + 8 * i]);
                aA = dot8h(va, w, aA);
                aB = dot8h(vb, w, aB);
            }
            zA += aA; zB += aB;
        }
    }

    if (u < 16) {
        float g = head_ln_g[d16], bb = head_ln_b[d16];
        float w0 = head_w[d16], w1 = head_w[16 + d16];
        float cvA = ln_norm16(zA, g, bb);
        float cvB = ln_norm16(zB, g, bb);
        float pA0 = cvA * w0, pA1 = cvA * w1;
        float pB0 = cvB * w0, pB1 = cvB * w1;
        #pragma unroll
        for (int off = 8; off >= 1; off >>= 1) {
            pA0 += __shfl_xor(pA0, off, 16);
            pA1 += __shfl_xor(pA1, off, 16);
            pB0 += __shfl_xor(pB0, off, 16);
            pB1 += __shfl_xor(pB1, off, 16);
        }
        if (u == 0) {
            float hb0 = head_b[0], hb1 = head_b[1];
            {
                float l0 = pA0 + hb0, l1 = pA1 + hb1;
                float mx = fmaxf(l0, l1);
                float e0 = __expf(l0 - mx), e1 = __expf(l1 - mx);
                float inv = 1.f / (e0 + e1);
                out[sA * 2 + 0] = e0 * inv;
                out[sA * 2 + 1] = e1 * inv;
            }
            {
                float l0 = pB0 + hb0, l1 = pB1 + hb1;
                float mx = fmaxf(l0, l1);
                float e0 = __expf(l0 - mx), e1 = __expf(l1 - mx);
                float inv = 1.f / (e0 + e1);
                out[(sA + 1) * 2 + 0] = e0 * inv;
                out[(sA + 1) * 2 + 1] = e1 * inv;
            }
        }
    }
}

extern "C" void kernel_launch(void* const* d_in, const int* in_sizes, int n_in,
                              void* d_out, int out_size, void* d_ws, size_t ws_size,
                              hipStream_t stream) {
    (void)n_in; (void)ws_size; (void)out_size;
    const float* a0  = (const float*)d_in[0];   // x
    const float* a1  = (const float*)d_in[1];   // conv_t_w
    const float* a2  = (const float*)d_in[2];   // conv_t_b
    const float* a3  = (const float*)d_in[3];   // bn1_g
    const float* a4  = (const float*)d_in[4];   // bn1_b
    const float* a5  = (const float*)d_in[5];   // bn1_m
    const float* a6  = (const float*)d_in[6];   // bn1_v
    const float* a7  = (const float*)d_in[7];   // conv_s_w
    const float* a8  = (const float*)d_in[8];   // conv_s_b
    const float* a9  = (const float*)d_in[9];   // bn2_g
    const float* a10 = (const float*)d_in[10];  // bn2_b
    const float* a11 = (const float*)d_in[11];  // bn2_m
    const float* a12 = (const float*)d_in[12];  // bn2_v
    const float* a13 = (const float*)d_in[13];  // proj_w
    const float* a14 = (const float*)d_in[14];  // proj_b
    const float* a15 = (const float*)d_in[15];  // cls_token
    const float* a16 = (const float*)d_in[16];  // pe
    const float* a17 = (const float*)d_in[17];  // qkv_w
    const float* a18 = (const float*)d_in[18];  // qkv_b
    const float* a19 = (const float*)d_in[19];  // out_w
    const float* a20 = (const float*)d_in[20];  // out_b
    const float* a21 = (const float*)d_in[21];  // ln1_g
    const float* a22 = (const float*)d_in[22];  // ln1_b
    const float* a23 = (const float*)d_in[23];  // ln2_g
    const float* a24 = (const float*)d_in[24];  // ln2_b
    const float* a25 = (const float*)d_in[25];  // mlp_w1
    const float* a26 = (const float*)d_in[26];  // mlp_b1
    const float* a27 = (const float*)d_in[27];  // mlp_w2
    const float* a28 = (const float*)d_in[28];  // mlp_b2
    const float* a29 = (const float*)d_in[29];  // head_ln_g
    const float* a30 = (const float*)d_in[30];  // head_ln_b
    const float* a31 = (const float*)d_in[31];  // head_w
    const float* a32 = (const float*)d_in[32];  // head_b

    int Bn = in_sizes[0] / (64 * 125);          // 2048
    float* tokws = (float*)d_ws;                // 2048 x 80 f32 = 640 KB

    eegnet_frontend<<<Bn, 128, 0, stream>>>(
        a0, a1, a2, a3, a4, a5, a6, a7, a8, a9, a10, a11, a12, a13, a14, tokws);

    eegnet_transformer<<<Bn / 4, 256, 0, stream>>>(
        a15, a16, a17, a18, a19, a20, a21, a22, a23, a24, a25, a26, a27, a28,
        a29, a30, a31, a32, tokws, (float*)d_out);
}

// Round 3
// 243.820 us; speedup vs baseline: 1.3250x; 1.3086x over previous
//
#include <hip/hip_runtime.h>

// Wave-synchronous fence: DS ops complete in order within a wave (ISA
// guarantee); this only stops the COMPILER from reordering/caching LDS.
#define WAVE_SYNC() do { asm volatile("" ::: "memory"); \
                         __builtin_amdgcn_wave_barrier(); \
                         asm volatile("" ::: "memory"); } while (0)

typedef _Float16 h2 __attribute__((ext_vector_type(2)));
typedef _Float16 h4 __attribute__((ext_vector_type(4)));
typedef _Float16 h8 __attribute__((ext_vector_type(8)));

__device__ __forceinline__ float fdot2(h2 a, h2 b, float c) {
#if defined(__has_builtin)
#if __has_builtin(__builtin_amdgcn_fdot2)
    return __builtin_amdgcn_fdot2(a, b, c, false);
#else
    return (float)a[0]*(float)b[0] + (float)a[1]*(float)b[1] + c;
#endif
#else
    return (float)a[0]*(float)b[0] + (float)a[1]*(float)b[1] + c;
#endif
}

__device__ __forceinline__ float dot8h(h8 a, h8 b, float c) {
    float s = c;
    #pragma unroll
    for (int i = 0; i < 4; ++i) {
        h2 x = {a[2*i], a[2*i+1]};
        h2 y = {b[2*i], b[2*i+1]};
        s = fdot2(x, y, s);
    }
    return s;
}

__device__ __forceinline__ float dot16h(h8 a0, h8 a1, h8 b0, h8 b1, float c) {
    return dot8h(a1, b1, dot8h(a0, b0, c));
}

__device__ __forceinline__ float ln_norm16(float z, float g, float bb) {
    float s = z, q = z * z;
    #pragma unroll
    for (int off = 8; off >= 1; off >>= 1) {
        s += __shfl_xor(s, off, 16);
        q += __shfl_xor(q, off, 16);
    }
    float mean = s * 0.0625f;
    float var  = q * 0.0625f - mean * mean;
    return (z - mean) * rsqrtf(var + 1e-5f) * g + bb;
}

__device__ __forceinline__ float gelu_exact(float a) {
    float xa = fabsf(a) * 0.70710678118654752f;
    float tt = 1.f / (1.f + 0.3275911f * xa);
    float poly = tt * (0.254829592f + tt * (-0.284496736f + tt * (1.421413741f
               + tt * (-1.453152027f + tt * 1.061405429f))));
    float erfv = 1.f - poly * __expf(-xa * xa);
    erfv = a >= 0.f ? erfv : -erfv;
    return 0.5f * a * (1.f + erfv);
}

// ========================= Kernel F: conv frontend ===========================
// v4: ONE-LINE FIX of the round-1/2 spill. hipcc treats the 2nd launch_bounds
// arg with CUDA semantics (min BLOCKS per EU): (128,4) -> 4 blk x 2 waves =
// 8 waves/EU -> VGPR cap 512/8 = 64 -> wt[63] spilled to scratch (169 MB
// writes, 156us). (128,2) -> 4 waves/EU -> cap 128 VGPRs: fits the ~100-VGPR
// peak (wt[63]+acc5[5]) with zero scratch, and 16 waves/CU is the grid cap
// anyway (2048 blocks x 2 waves / 256 CUs).
// - Stage 1 loop order: c outer (streamed), o inner (16 accumulators); xv
//   loads coalesced (lane = time index); conv_s_w reads wave-uniform.
// - XSP f16, stride 210 halfs (105 === 9 mod 32, gcd(9,32)=1 -> conflict-free
//   column reads). LDS 8.5 KB.
#define FS_XSTR 210         // XSP row stride in halfs
#define FS_PF   1680        // float idx of pool region (= half idx 3360)
#define FS_TOTF 2128        // 8512 B total LDS

extern "C" __global__ __launch_bounds__(128, 2)
void eegnet_frontend(
    const float* __restrict__ x,
    const float* __restrict__ conv_t_w, const float* __restrict__ conv_t_b,
    const float* __restrict__ bn1_g, const float* __restrict__ bn1_b,
    const float* __restrict__ bn1_m, const float* __restrict__ bn1_v,
    const float* __restrict__ conv_s_w, const float* __restrict__ conv_s_b,
    const float* __restrict__ bn2_g, const float* __restrict__ bn2_b,
    const float* __restrict__ bn2_m, const float* __restrict__ bn2_v,
    const float* __restrict__ proj_w, const float* __restrict__ proj_b,
    float* __restrict__ tokws)
{
    __shared__ __align__(16) float sm[FS_TOTF];
    _Float16* smh = reinterpret_cast<_Float16*>(sm);
    const int b   = blockIdx.x;
    const int tid = threadIdx.x;

    // ---- zero the pad zones of XSP: per row [0,32) and [157,210) ----
    for (int i = tid; i < 16 * 85; i += 128) {
        int row = i / 85, k = i - row * 85;
        int off = (k < 32) ? k : (k + 125);
        smh[row * FS_XSTR + off] = (_Float16)0.f;
    }

    // ---- stage 1: spatial conv direct from global; one time-column/lane ----
    // Loop order: c outer (streamed), o inner (16 accumulators). Only ~25 live
    // VGPRs; conv_s_w reads are wave-uniform -> s_loads.
    if (tid < 125) {
        const float* xb = x + (size_t)b * 8000 + tid;
        float acc[16];
        #pragma unroll
        for (int o = 0; o < 16; ++o) acc[o] = 0.f;
        #pragma unroll 8
        for (int c = 0; c < 64; ++c) {
            float xv = xb[c * 125];                      // coalesced dword
            #pragma unroll
            for (int o = 0; o < 16; ++o)
                acc[o] += conv_s_w[o * 64 + c] * xv;     // uniform -> s_load
        }
        #pragma unroll
        for (int o = 0; o < 16; ++o)
            smh[o * FS_XSTR + 32 + tid] = (_Float16)acc[o];
    }

    __syncthreads();   // XSP (both waves) ready

    // ---- fused BN constants + temporal taps ----
    const int oo = tid & 15, qg = tid >> 4, gg = oo >> 1;
    float sa, cc;
    {
        float s1 = bn1_g[gg] * rsqrtf(bn1_v[gg] + 1e-5f);
        float b1 = (conv_t_b[gg] - bn1_m[gg]) * s1 + bn1_b[gg];
        float s2 = bn2_g[oo] * rsqrtf(bn2_v[oo] + 1e-5f);
        float ssum = 0.f;
        const float4* csw = reinterpret_cast<const float4*>(conv_s_w + oo * 64);
        #pragma unroll
        for (int i = 0; i < 16; ++i) {
            float4 v = csw[i];
            ssum += v.x + v.y + v.z + v.w;
        }
        sa = s1 * s2;
        cc = (b1 * ssum + conv_s_b[oo] - bn2_m[oo]) * s2 + bn2_b[oo];
    }
    float wt[63];
    #pragma unroll
    for (int k = 0; k < 63; ++k) wt[k] = conv_t_w[gg * 63 + k];

    // ---- stage 2: temporal conv + BN + ELU + avg-pool (4 slots/lane) ----
    #pragma unroll 2
    for (int jj = 0; jj < 4; ++jj) {
        int j  = qg * 4 + jj;            // 0..31, slots 25..31 are clamped dups
        int jc = min(j, 24);
        int base = oo * FS_XSTR + 5 * jc + 1;
        float acc5[5] = {0.f, 0.f, 0.f, 0.f, 0.f};
        #pragma unroll
        for (int m = 0; m < 67; ++m) {
            float xv = (float)smh[base + m];
            #pragma unroll
            for (int u = 0; u < 5; ++u)
                if (u <= m && m - u <= 62) acc5[u] += wt[m - u] * xv;
        }
        float psum = 0.f;
        #pragma unroll
        for (int u = 0; u < 5; ++u) {
            float v = acc5[u] * sa + cc;
            psum += (v > 0.f) ? v : (__expf(v) - 1.f);
        }
        if (j == jc) sm[FS_PF + oo * 28 + j] = psum * 0.2f;
    }

    __syncthreads();   // pooled values ready

    // ---- stage 3: token projection -> global TOK ----
    if (tid < 80) {
        int p = tid >> 4, dd = tid & 15;
        float acc = proj_b[dd];
        const float4* wp = reinterpret_cast<const float4*>(proj_w + dd * 80);
        #pragma unroll
        for (int i = 0; i < 20; ++i) {
            float4 w4 = wp[i];
            acc += w4.x * sm[FS_PF + ((4*i+0)/5) * 28 + p * 5 + ((4*i+0)%5)];
            acc += w4.y * sm[FS_PF + ((4*i+1)/5) * 28 + p * 5 + ((4*i+1)%5)];
            acc += w4.z * sm[FS_PF + ((4*i+2)/5) * 28 + p * 5 + ((4*i+2)%5)];
            acc += w4.w * sm[FS_PF + ((4*i+3)/5) * 28 + p * 5 + ((4*i+3)%5)];
        }
        tokws[b * 80 + p * 16 + dd] = acc;
    }
}

// ===================== Kernel T: transformer + head (f16 operands) ===========
// Unchanged this round (passed, absmax 3.9e-3). Next target: grid-limited
// occupancy (512 blocks = 2 blocks/CU).
#define WQKVH 0          // 192 rows, stride 24 halfs
#define WOUTH 4608       // 16 rows, stride 72
#define WM1H  5760       // 32 rows, stride 24
#define WM2H  6528       // 16 rows, stride 40
#define BQKVF 3584       // float idx
#define BOUTF 3776
#define BM1F  3792
#define BM2F  3824
#define LN1GF 3840
#define LN1BF 3856
#define LN2GF 3872
#define LN2BF 3888
#define SCR0  7808       // half idx
#define SSTRH 1584
#define SH1H  0
#define SQKVH 144
#define SMHSH 1344
#define T_BYTES 28288

extern "C" __global__ __launch_bounds__(256, 2)
void eegnet_transformer(
    const float* __restrict__ cls_token, const float* __restrict__ pe,
    const float* __restrict__ qkv_w, const float* __restrict__ qkv_b,
    const float* __restrict__ out_w, const float* __restrict__ out_b,
    const float* __restrict__ ln1_g, const float* __restrict__ ln1_b,
    const float* __restrict__ ln2_g, const float* __restrict__ ln2_b,
    const float* __restrict__ mlp_w1, const float* __restrict__ mlp_b1,
    const float* __restrict__ mlp_w2, const float* __restrict__ mlp_b2,
    const float* __restrict__ head_ln_g, const float* __restrict__ head_ln_b,
    const float* __restrict__ head_w, const float* __restrict__ head_b,
    const float* __restrict__ tokws, float* __restrict__ out)
{
    __shared__ __align__(16) unsigned char smb[T_BYTES];
    float*    smf = reinterpret_cast<float*>(smb);
    _Float16* smh = reinterpret_cast<_Float16*>(smb);

    const int tid = threadIdx.x;
    const int ss  = tid >> 7;
    const int u   = tid & 127;
    const int sA  = blockIdx.x * 4 + ss * 2;
    const int d16 = u & 15, qg = u >> 4;
    const int t6c = min(qg, 5);
    const int wav = u >> 6, al = u & 63;
    const int sbA = SCR0 + (ss * 2    ) * SSTRH;
    const int sbB = SCR0 + (ss * 2 + 1) * SSTRH;

    float zA, zB;
    {
        float peV = pe[t6c * 16 + d16];
        if (t6c == 0) {
            float cv = cls_token[d16];
            zA = cv + peV; zB = cv + peV;
        } else {
            zA = tokws[(sA    ) * 80 + (t6c - 1) * 16 + d16] + peV;
            zB = tokws[(sA + 1) * 80 + (t6c - 1) * 16 + d16] + peV;
        }
    }

    #pragma unroll 1
    for (int li = 0; li < 6; ++li) {
        __syncthreads();

        {
            const float4* s1 = reinterpret_cast<const float4*>(qkv_w + li * 3072);
            #pragma unroll
            for (int it = 0; it < 3; ++it) {
                int i = tid + it * 256;
                float4 v = s1[i];
                int j = i >> 2, k = (i & 3) << 2;
                h4 hv = {(_Float16)v.x, (_Float16)v.y, (_Float16)v.z, (_Float16)v.w};
                *reinterpret_cast<h4*>(&smh[WQKVH + j * 24 + k]) = hv;
            }
            {
                float4 v = reinterpret_cast<const float4*>(out_w + li * 1024)[tid];
                int j = tid >> 4, k = (tid & 15) << 2;
                h4 hv = {(_Float16)v.x, (_Float16)v.y, (_Float16)v.z, (_Float16)v.w};
                *reinterpret_cast<h4*>(&smh[WOUTH + j * 72 + k]) = hv;
            }
            if (tid < 128) {
                float4 v = reinterpret_cast<const float4*>(mlp_w1 + li * 512)[tid];
                int j = tid >> 2, k = (tid & 3) << 2;
                h4 hv = {(_Float16)v.x, (_Float16)v.y, (_Float16)v.z, (_Float16)v.w};
                *reinterpret_cast<h4*>(&smh[WM1H + j * 24 + k]) = hv;
            } else {
                int i = tid - 128;
                float4 v = reinterpret_cast<const float4*>(mlp_w2 + li * 512)[i];
                int j = i >> 3, k = (i & 7) << 2;
                h4 hv = {(_Float16)v.x, (_Float16)v.y, (_Float16)v.z, (_Float16)v.w};
                *reinterpret_cast<h4*>(&smh[WM2H + j * 40 + k]) = hv;
            }
            if (tid < 192) smf[BQKVF + tid] = qkv_b[li * 192 + tid];
            else if (tid < 208) smf[BOUTF + tid - 192] = out_b[li * 16 + tid - 192];
            else if (tid < 240) smf[BM1F + tid - 208]  = mlp_b1[li * 32 + tid - 208];
            else               smf[BM2F + tid - 240]  = mlp_b2[li * 16 + tid - 240];
            if (tid >= 64 && tid < 80)        smf[LN1GF + tid - 64]  = ln1_g[li * 16 + tid - 64];
            else if (tid >= 80 && tid < 96)   smf[LN1BF + tid - 80]  = ln1_b[li * 16 + tid - 80];
            else if (tid >= 96 && tid < 112)  smf[LN2GF + tid - 96]  = ln2_g[li * 16 + tid - 96];
            else if (tid >= 112 && tid < 128) smf[LN2BF + tid - 112] = ln2_b[li * 16 + tid - 112];
        }
        __syncthreads();

        {
            float g = smf[LN1GF + d16], bb = smf[LN1BF + d16];
            smh[sbA + SH1H + t6c * 24 + d16] = (_Float16)ln_norm16(zA, g, bb);
            smh[sbB + SH1H + t6c * 24 + d16] = (_Float16)ln_norm16(zB, g, bb);
        }
        WAVE_SYNC();

        h8 hA0 = *reinterpret_cast<const h8*>(&smh[sbA + SH1H + t6c * 24]);
        h8 hA1 = *reinterpret_cast<const h8*>(&smh[sbA + SH1H + t6c * 24 + 8]);
        h8 hB0 = *reinterpret_cast<const h8*>(&smh[sbB + SH1H + t6c * 24]);
        h8 hB1 = *reinterpret_cast<const h8*>(&smh[sbB + SH1H + t6c * 24 + 8]);

        #pragma unroll 2
        for (int r = 0; r < 12; ++r) {
            int j = d16 + 16 * r;
            h8 w0 = *reinterpret_cast<const h8*>(&smh[WQKVH + j * 24]);
            h8 w1 = *reinterpret_cast<const h8*>(&smh[WQKVH + j * 24 + 8]);
            float bb = smf[BQKVF + j];
            smh[sbA + SQKVH + t6c * 200 + j] = (_Float16)dot16h(hA0, hA1, w0, w1, bb);
            smh[sbB + SQKVH + t6c * 200 + j] = (_Float16)dot16h(hB0, hB1, w0, w1, bb);
        }
        __syncthreads();

        {
            bool act = (wav == 0) ? (al < 32) : (al < 16);
            if (act) {
                int h  = al & 7;
                int qs = (wav == 0) ? (al >> 3) : 4 + (al >> 3);
                const int qoffA = sbA + SQKVH + qs * 200 + h * 8;
                const int qoffB = sbB + SQKVH + qs * 200 + h * 8;
                h8 qA = *reinterpret_cast<const h8*>(&smh[qoffA]);
                h8 qB = *reinterpret_cast<const h8*>(&smh[qoffB]);
                float scA[6], scB[6];
                #pragma unroll
                for (int t = 0; t < 6; ++t) {
                    h8 kA = *reinterpret_cast<const h8*>(&smh[sbA + SQKVH + t * 200 + 64 + h * 8]);
                    h8 kB = *reinterpret_cast<const h8*>(&smh[sbB + SQKVH + t * 200 + 64 + h * 8]);
                    scA[t] = dot8h(qA, kA, 0.f) * 0.35355339059327373f;
                    scB[t] = dot8h(qB, kB, 0.f) * 0.35355339059327373f;
                }
                float mxA = scA[0], mxB = scB[0];
                #pragma unroll
                for (int t = 1; t < 6; ++t) { mxA = fmaxf(mxA, scA[t]); mxB = fmaxf(mxB, scB[t]); }
                float suA = 0.f, suB = 0.f;
                #pragma unroll
                for (int t = 0; t < 6; ++t) {
                    scA[t] = __expf(scA[t] - mxA); suA += scA[t];
                    scB[t] = __expf(scB[t] - mxB); suB += scB[t];
                }
                float ivA = 1.f / suA, ivB = 1.f / suB;
                h2 oA[4], oB[4];
                #pragma unroll
                for (int k2 = 0; k2 < 4; ++k2) { oA[k2] = h2{0, 0}; oB[k2] = h2{0, 0}; }
                #pragma unroll
                for (int t = 0; t < 6; ++t) {
                    h8 vA = *reinterpret_cast<const h8*>(&smh[sbA + SQKVH + t * 200 + 128 + h * 8]);
                    h8 vB = *reinterpret_cast<const h8*>(&smh[sbB + SQKVH + t * 200 + 128 + h * 8]);
                    _Float16 aa = (_Float16)(scA[t] * ivA);
                    _Float16 ab = (_Float16)(scB[t] * ivB);
                    h2 av = {aa, aa}, bv = {ab, ab};
                    #pragma unroll
                    for (int k2 = 0; k2 < 4; ++k2) {
                        h2 va = {vA[2*k2], vA[2*k2+1]};
                        h2 vb = {vB[2*k2], vB[2*k2+1]};
                        oA[k2] += av * va;
                        oB[k2] += bv * vb;
                    }
                }
                h8 stA, stB;
                #pragma unroll
                for (int k2 = 0; k2 < 4; ++k2) {
                    stA[2*k2] = oA[k2][0]; stA[2*k2+1] = oA[k2][1];
                    stB[2*k2] = oB[k2][0]; stB[2*k2+1] = oB[k2][1];
                }
                *reinterpret_cast<h8*>(&smh[qoffA]) = stA;
                *reinterpret_cast<h8*>(&smh[qoffB]) = stB;
            }
        }
        WAVE_SYNC();

        {
            float aA = smf[BOUTF + d16], aB = aA;
            #pragma unroll
            for (int i = 0; i < 8; ++i) {
                h8 w  = *reinterpret_cast<const h8*>(&smh[WOUTH + d16 * 72 + 8 * i]);
                h8 va = *reinterpret_cast<const h8*>(&smh[sbA + SQKVH + t6c * 200 + 8 * i]);
                h8 vb = *reinterpret_cast<const h8*>(&smh[sbB + SQKVH + t6c * 200 + 8 * i]);
                aA = dot8h(va, w, aA);
                aB = dot8h(vb, w, aB);
            }
            zA += aA; zB += aB;
        }

        {
            float g = smf[LN2GF + d16], bb = smf[LN2BF + d16];
            smh[sbA + SH1H + t6c * 24 + d16] = (_Float16)ln_norm16(zA, g, bb);
            smh[sbB + SH1H + t6c * 24 + d16] = (_Float16)ln_norm16(zB, g, bb);
        }
        WAVE_SYNC();
        hA0 = *reinterpret_cast<const h8*>(&smh[sbA + SH1H + t6c * 24]);
        hA1 = *reinterpret_cast<const h8*>(&smh[sbA + SH1H + t6c * 24 + 8]);
        hB0 = *reinterpret_cast<const h8*>(&smh[sbB + SH1H + t6c * 24]);
        hB1 = *reinterpret_cast<const h8*>(&smh[sbB + SH1H + t6c * 24 + 8]);

        #pragma unroll
        for (int r = 0; r < 2; ++r) {
            int uu = d16 + 16 * r;
            h8 w0 = *reinterpret_cast<const h8*>(&smh[WM1H + uu * 24]);
            h8 w1 = *reinterpret_cast<const h8*>(&smh[WM1H + uu * 24 + 8]);
            float bb = smf[BM1F + uu];
            float aA = dot16h(hA0, hA1, w0, w1, bb);
            float aB = dot16h(hB0, hB1, w0, w1, bb);
            smh[sbA + SMHSH + t6c * 40 + uu] = (_Float16)gelu_exact(aA);
            smh[sbB + SMHSH + t6c * 40 + uu] = (_Float16)gelu_exact(aB);
        }
        WAVE_SYNC();

        {
            float aA = smf[BM2F + d16], aB = aA;
            #pragma unroll
            for (int i = 0; i < 4; ++i) {
                h8 w  = *reinterpret_cast<const h8*>(&smh[WM2H + d16 * 40 + 8 * i]);
                h8 va = *reinterpret_cast<const h8*>(&smh[sbA + SMHSH + t6c * 40 + 8 * i]);
                h8 vb = *reinterpret_cast<const h8*>(&smh[sbB + SMHSH + t6c * 40 + 8 * i]);
                aA = dot8h(va, w, aA);
                aB = dot8h(vb, w, aB);
            }
            zA += aA; zB += aB;
        }
    }

    if (u < 16) {
        float g = head_ln_g[d16], bb = head_ln_b[d16];
        float w0 = head_w[d16], w1 = head_w[16 + d16];
        float cvA = ln_norm16(zA, g, bb);
        float cvB = ln_norm16(zB, g, bb);
        float pA0 = cvA * w0, pA1 = cvA * w1;
        float pB0 = cvB * w0, pB1 = cvB * w1;
        #pragma unroll
        for (int off = 8; off >= 1; off >>= 1) {
            pA0 += __shfl_xor(pA0, off, 16);
            pA1 += __shfl_xor(pA1, off, 16);
            pB0 += __shfl_xor(pB0, off, 16);
            pB1 += __shfl_xor(pB1, off, 16);
        }
        if (u == 0) {
            float hb0 = head_b[0], hb1 = head_b[1];
            {
                float l0 = pA0 + hb0, l1 = pA1 + hb1;
                float mx = fmaxf(l0, l1);
                float e0 = __expf(l0 - mx), e1 = __expf(l1 - mx);
                float inv = 1.f / (e0 + e1);
                out[sA * 2 + 0] = e0 * inv;
                out[sA * 2 + 1] = e1 * inv;
            }
            {
                float l0 = pB0 + hb0, l1 = pB1 + hb1;
                float mx = fmaxf(l0, l1);
                float e0 = __expf(l0 - mx), e1 = __expf(l1 - mx);
                float inv = 1.f / (e0 + e1);
                out[(sA + 1) * 2 + 0] = e0 * inv;
                out[(sA + 1) * 2 + 1] = e1 * inv;
            }
        }
    }
}

extern "C" void kernel_launch(void* const* d_in, const int* in_sizes, int n_in,
                              void* d_out, int out_size, void* d_ws, size_t ws_size,
                              hipStream_t stream) {
    (void)n_in; (void)ws_size; (void)out_size;
    const float* a0  = (const float*)d_in[0];   // x
    const float* a1  = (const float*)d_in[1];   // conv_t_w
    const float* a2  = (const float*)d_in[2];   // conv_t_b
    const float* a3  = (const float*)d_in[3];   // bn1_g
    const float* a4  = (const float*)d_in[4];   // bn1_b
    const float* a5  = (const float*)d_in[5];   // bn1_m
    const float* a6  = (const float*)d_in[6];   // bn1_v
    const float* a7  = (const float*)d_in[7];   // conv_s_w
    const float* a8  = (const float*)d_in[8];   // conv_s_b
    const float* a9  = (const float*)d_in[9];   // bn2_g
    const float* a10 = (const float*)d_in[10];  // bn2_b
    const float* a11 = (const float*)d_in[11];  // bn2_m
    const float* a12 = (const float*)d_in[12];  // bn2_v
    const float* a13 = (const float*)d_in[13];  // proj_w
    const float* a14 = (const float*)d_in[14];  // proj_b
    const float* a15 = (const float*)d_in[15];  // cls_token
    const float* a16 = (const float*)d_in[16];  // pe
    const float* a17 = (const float*)d_in[17];  // qkv_w
    const float* a18 = (const float*)d_in[18];  // qkv_b
    const float* a19 = (const float*)d_in[19];  // out_w
    const float* a20 = (const float*)d_in[20];  // out_b
    const float* a21 = (const float*)d_in[21];  // ln1_g
    const float* a22 = (const float*)d_in[22];  // ln1_b
    const float* a23 = (const float*)d_in[23];  // ln2_g
    const float* a24 = (const float*)d_in[24];  // ln2_b
    const float* a25 = (const float*)d_in[25];  // mlp_w1
    const float* a26 = (const float*)d_in[26];  // mlp_b1
    const float* a27 = (const float*)d_in[27];  // mlp_w2
    const float* a28 = (const float*)d_in[28];  // mlp_b2
    const float* a29 = (const float*)d_in[29];  // head_ln_g
    const float* a30 = (const float*)d_in[30];  // head_ln_b
    const float* a31 = (const float*)d_in[31];  // head_w
    const float* a32 = (const float*)d_in[32];  // head_b

    int Bn = in_sizes[0] / (64 * 125);          // 2048
    float* tokws = (float*)d_ws;                // 2048 x 80 f32 = 640 KB

    eegnet_frontend<<<Bn, 128, 0, stream>>>(
        a0, a1, a2, a3, a4, a5, a6, a7, a8, a9, a10, a11, a12, a13, a14, tokws);

    eegnet_transformer<<<Bn / 4, 256, 0, stream>>>(
        a15, a16, a17, a18, a19, a20, a21, a22, a23, a24, a25, a26, a27, a28,
        a29, a30, a31, a32, tokws, (float*)d_out);
}

// Round 4
// 240.007 us; speedup vs baseline: 1.3460x; 1.0159x over previous
//
#include <hip/hip_runtime.h>

// Wave-synchronous fence: DS ops complete in order within a wave (ISA
// guarantee); this only stops the COMPILER from reordering/caching LDS.
#define WAVE_SYNC() do { asm volatile("" ::: "memory"); \
                         __builtin_amdgcn_wave_barrier(); \
                         asm volatile("" ::: "memory"); } while (0)

typedef _Float16 h2 __attribute__((ext_vector_type(2)));
typedef _Float16 h4 __attribute__((ext_vector_type(4)));
typedef _Float16 h8 __attribute__((ext_vector_type(8)));

__device__ __forceinline__ float fdot2(h2 a, h2 b, float c) {
#if defined(__has_builtin)
#if __has_builtin(__builtin_amdgcn_fdot2)
    return __builtin_amdgcn_fdot2(a, b, c, false);
#else
    return (float)a[0]*(float)b[0] + (float)a[1]*(float)b[1] + c;
#endif
#else
    return (float)a[0]*(float)b[0] + (float)a[1]*(float)b[1] + c;
#endif
}

__device__ __forceinline__ float dot8h(h8 a, h8 b, float c) {
    float s = c;
    #pragma unroll
    for (int i = 0; i < 4; ++i) {
        h2 x = {a[2*i], a[2*i+1]};
        h2 y = {b[2*i], b[2*i+1]};
        s = fdot2(x, y, s);
    }
    return s;
}

__device__ __forceinline__ float dot16h(h8 a0, h8 a1, h8 b0, h8 b1, float c) {
    return dot8h(a1, b1, dot8h(a0, b0, c));
}

__device__ __forceinline__ float ln_norm16(float z, float g, float bb) {
    float s = z, q = z * z;
    #pragma unroll
    for (int off = 8; off >= 1; off >>= 1) {
        s += __shfl_xor(s, off, 16);
        q += __shfl_xor(q, off, 16);
    }
    float mean = s * 0.0625f;
    float var  = q * 0.0625f - mean * mean;
    return (z - mean) * rsqrtf(var + 1e-5f) * g + bb;
}

__device__ __forceinline__ float gelu_exact(float a) {
    float xa = fabsf(a) * 0.70710678118654752f;
    float tt = 1.f / (1.f + 0.3275911f * xa);
    float poly = tt * (0.254829592f + tt * (-0.284496736f + tt * (1.421413741f
               + tt * (-1.453152027f + tt * 1.061405429f))));
    float erfv = 1.f - poly * __expf(-xa * xa);
    erfv = a >= 0.f ? erfv : -erfv;
    return 0.5f * a * (1.f + erfv);
}

// ========================= Kernel F: conv frontend ===========================
// v5: stage 1 is pure LDS (no global/scalar loads in the hot loop).
// - Stage 0a: x -> xr f16 ring (16 independent float4 loads/lane = ONE latency
//   window). v4's 500B-strided dword reads in stage 1 were the 78us regression.
// - Stage 0b: conv_s_w -> LDS, packed f16 [c2][o] h2 pairs (2 KB). Stage 1
//   consumes weights via 4x ds_read_b128 broadcast per c2 + 16 v_dot2.
//   This removes the 1024 per-wave weight loads the compiler was re-issuing
//   (SGPR budget can't hold 16 w x unroll-8 -> load+wait every iter).
// - XSP (f16, stride 210) and pool alias the dead xr ring after a barrier.
// - LDS: xr 16000 B | wlds 2048 B at byte 16000 -> 18048 B, 8 blocks/CU.
#define F5_XSTR 210         // XSP row stride in halfs
#define F5_PF   1680        // f32 idx of pool region (byte 6720, aliases xr)
#define F5_WLH  8000        // half idx of packed weights (byte 16000)
#define F5_TOTF 4512        // 18048 B total LDS

extern "C" __global__ __launch_bounds__(128, 2)
void eegnet_frontend(
    const float* __restrict__ x,
    const float* __restrict__ conv_t_w, const float* __restrict__ conv_t_b,
    const float* __restrict__ bn1_g, const float* __restrict__ bn1_b,
    const float* __restrict__ bn1_m, const float* __restrict__ bn1_v,
    const float* __restrict__ conv_s_w, const float* __restrict__ conv_s_b,
    const float* __restrict__ bn2_g, const float* __restrict__ bn2_b,
    const float* __restrict__ bn2_m, const float* __restrict__ bn2_v,
    const float* __restrict__ proj_w, const float* __restrict__ proj_b,
    float* __restrict__ tokws)
{
    __shared__ __align__(16) float sm[F5_TOTF];
    _Float16* smh = reinterpret_cast<_Float16*>(sm);
    const int b   = blockIdx.x;
    const int tid = threadIdx.x;

    // ---- stage 0a: x -> xr f16 ring (coalesced float4, one latency window) --
    {
        const float4* xb4 = reinterpret_cast<const float4*>(x + (size_t)b * 8000);
        #pragma unroll
        for (int k = 0; k < 16; ++k) {
            int g = min(tid + k * 128, 1999);     // tail lanes dup (same value)
            float4 v = xb4[g];
            h4 hv = {(_Float16)v.x, (_Float16)v.y, (_Float16)v.z, (_Float16)v.w};
            *reinterpret_cast<h4*>(&smh[4 * g]) = hv;
        }
    }
    // ---- stage 0b: conv_s_w -> wlds f16 [c2][o] h2 pairs (2 KB, one-time) ---
    {
        #pragma unroll
        for (int k = 0; k < 4; ++k) {
            int i  = tid + k * 128;               // 0..511
            int c2 = i & 31, o = i >> 5;
            float2 wv = *reinterpret_cast<const float2*>(conv_s_w + o * 64 + 2 * c2);
            h2 hp = {(_Float16)wv.x, (_Float16)wv.y};
            *reinterpret_cast<h2*>(&smh[F5_WLH + (c2 * 16 + o) * 2]) = hp;
        }
    }
    __syncthreads();   // xr + wlds ready

    // ---- stage 1: spatial conv, pure LDS ------------------------------------
    float acc[16];
    #pragma unroll
    for (int o = 0; o < 16; ++o) acc[o] = 0.f;
    if (tid < 125) {
        #pragma unroll 4
        for (int c2 = 0; c2 < 32; ++c2) {
            h2 xp = { smh[(2 * c2) * 125 + tid], smh[(2 * c2 + 1) * 125 + tid] };
            const h8* wrow = reinterpret_cast<const h8*>(&smh[F5_WLH + c2 * 32]);
            h8 w0 = wrow[0], w1 = wrow[1], w2 = wrow[2], w3 = wrow[3];
            #pragma unroll
            for (int o = 0; o < 4; ++o) {
                h2 p0 = {w0[2*o], w0[2*o+1]};
                h2 p1 = {w1[2*o], w1[2*o+1]};
                h2 p2 = {w2[2*o], w2[2*o+1]};
                h2 p3 = {w3[2*o], w3[2*o+1]};
                acc[o]      = fdot2(p0, xp, acc[o]);
                acc[4 + o]  = fdot2(p1, xp, acc[4 + o]);
                acc[8 + o]  = fdot2(p2, xp, acc[8 + o]);
                acc[12 + o] = fdot2(p3, xp, acc[12 + o]);
            }
        }
    }
    __syncthreads();   // all xr reads retired before aliased XSP writes

    // ---- pad-zero XSP edges + write spatial-conv rows (aliases xr) ----------
    for (int i = tid; i < 16 * 85; i += 128) {
        int row = i / 85, k = i - row * 85;
        int off = (k < 32) ? k : (k + 125);
        smh[row * F5_XSTR + off] = (_Float16)0.f;
    }
    if (tid < 125) {
        #pragma unroll
        for (int o = 0; o < 16; ++o)
            smh[o * F5_XSTR + 32 + tid] = (_Float16)acc[o];
    }
    __syncthreads();   // XSP ready

    // ---- fused BN constants + temporal taps ----
    const int oo = tid & 15, qg = tid >> 4, gg = oo >> 1;
    float sa, cc;
    {
        float s1 = bn1_g[gg] * rsqrtf(bn1_v[gg] + 1e-5f);
        float b1 = (conv_t_b[gg] - bn1_m[gg]) * s1 + bn1_b[gg];
        float s2 = bn2_g[oo] * rsqrtf(bn2_v[oo] + 1e-5f);
        float ssum = 0.f;
        const float4* csw = reinterpret_cast<const float4*>(conv_s_w + oo * 64);
        #pragma unroll
        for (int i = 0; i < 16; ++i) {
            float4 v = csw[i];
            ssum += v.x + v.y + v.z + v.w;
        }
        sa = s1 * s2;
        cc = (b1 * ssum + conv_s_b[oo] - bn2_m[oo]) * s2 + bn2_b[oo];
    }
    float wt[63];
    #pragma unroll
    for (int k = 0; k < 63; ++k) wt[k] = conv_t_w[gg * 63 + k];

    // ---- stage 2: temporal conv + BN + ELU + avg-pool (4 slots/lane) ----
    #pragma unroll 2
    for (int jj = 0; jj < 4; ++jj) {
        int j  = qg * 4 + jj;            // 0..31, slots 25..31 are clamped dups
        int jc = min(j, 24);
        int base = oo * F5_XSTR + 5 * jc + 1;
        float acc5[5] = {0.f, 0.f, 0.f, 0.f, 0.f};
        #pragma unroll
        for (int m = 0; m < 67; ++m) {
            float xv = (float)smh[base + m];
            #pragma unroll
            for (int u = 0; u < 5; ++u)
                if (u <= m && m - u <= 62) acc5[u] += wt[m - u] * xv;
        }
        float psum = 0.f;
        #pragma unroll
        for (int u = 0; u < 5; ++u) {
            float v = acc5[u] * sa + cc;
            psum += (v > 0.f) ? v : (__expf(v) - 1.f);
        }
        if (j == jc) sm[F5_PF + oo * 28 + j] = psum * 0.2f;
    }

    __syncthreads();   // pooled values ready

    // ---- stage 3: token projection -> global TOK ----
    if (tid < 80) {
        int p = tid >> 4, dd = tid & 15;
        float acc3 = proj_b[dd];
        const float4* wp = reinterpret_cast<const float4*>(proj_w + dd * 80);
        #pragma unroll
        for (int i = 0; i < 20; ++i) {
            float4 w4 = wp[i];
            acc3 += w4.x * sm[F5_PF + ((4*i+0)/5) * 28 + p * 5 + ((4*i+0)%5)];
            acc3 += w4.y * sm[F5_PF + ((4*i+1)/5) * 28 + p * 5 + ((4*i+1)%5)];
            acc3 += w4.z * sm[F5_PF + ((4*i+2)/5) * 28 + p * 5 + ((4*i+2)%5)];
            acc3 += w4.w * sm[F5_PF + ((4*i+3)/5) * 28 + p * 5 + ((4*i+3)%5)];
        }
        tokws[b * 80 + p * 16 + dd] = acc3;
    }
}

// ===================== Kernel T: transformer + head (f16 operands) ===========
// v5: 1 sample per 128-thread block (grid 2048) instead of 4 per 256 (grid
// 512). Per-CU waves 8 -> 16 (was grid-capped at 25% occupancy). LDS =
// weights 15616 B + one scratch 3168 B = 18784 B -> 8 blocks/CU. Weight
// staging runs 4x more often but is L2-resident (~0.2 MB working set).
// Cross-wave deps: every scratch row is produced+consumed by the same
// 16-thread group (same wave) except K/V in attention, which sits behind the
// existing __syncthreads. Same WAVE_SYNC structure as the 256-thr version.
#define WQKVH 0          // 192 rows, stride 24 halfs
#define WOUTH 4608       // 16 rows, stride 72
#define WM1H  5760       // 32 rows, stride 24
#define WM2H  6528       // 16 rows, stride 40
#define BQKVF 3584       // float idx
#define BOUTF 3776
#define BM1F  3792
#define BM2F  3824
#define LN1GF 3840
#define LN1BF 3856
#define LN2GF 3872
#define LN2BF 3888
#define SCR0  7808       // half idx
#define SSTRH 1584
#define SH1H  0
#define SQKVH 144
#define SMHSH 1344
#define T_BYTES 18784

extern "C" __global__ __launch_bounds__(128, 2)
void eegnet_transformer(
    const float* __restrict__ cls_token, const float* __restrict__ pe,
    const float* __restrict__ qkv_w, const float* __restrict__ qkv_b,
    const float* __restrict__ out_w, const float* __restrict__ out_b,
    const float* __restrict__ ln1_g, const float* __restrict__ ln1_b,
    const float* __restrict__ ln2_g, const float* __restrict__ ln2_b,
    const float* __restrict__ mlp_w1, const float* __restrict__ mlp_b1,
    const float* __restrict__ mlp_w2, const float* __restrict__ mlp_b2,
    const float* __restrict__ head_ln_g, const float* __restrict__ head_ln_b,
    const float* __restrict__ head_w, const float* __restrict__ head_b,
    const float* __restrict__ tokws, float* __restrict__ out)
{
    __shared__ __align__(16) unsigned char smb[T_BYTES];
    float*    smf = reinterpret_cast<float*>(smb);
    _Float16* smh = reinterpret_cast<_Float16*>(smb);

    const int tid = threadIdx.x;
    const int sA  = blockIdx.x;
    const int d16 = tid & 15, qg = tid >> 4;
    const int t6c = min(qg, 5);
    const int wav = tid >> 6, al = tid & 63;
    const int sb  = SCR0;

    float zA;
    {
        float peV = pe[t6c * 16 + d16];
        if (t6c == 0) zA = cls_token[d16] + peV;
        else          zA = tokws[sA * 80 + (t6c - 1) * 16 + d16] + peV;
    }

    #pragma unroll 1
    for (int li = 0; li < 6; ++li) {
        __syncthreads();

        {
            const float4* s1 = reinterpret_cast<const float4*>(qkv_w + li * 3072);
            #pragma unroll
            for (int it = 0; it < 6; ++it) {
                int i = tid + it * 128;           // 768 float4
                float4 v = s1[i];
                int j = i >> 2, k = (i & 3) << 2;
                h4 hv = {(_Float16)v.x, (_Float16)v.y, (_Float16)v.z, (_Float16)v.w};
                *reinterpret_cast<h4*>(&smh[WQKVH + j * 24 + k]) = hv;
            }
            const float4* s2 = reinterpret_cast<const float4*>(out_w + li * 1024);
            #pragma unroll
            for (int it = 0; it < 2; ++it) {
                int i = tid + it * 128;           // 256 float4
                float4 v = s2[i];
                int j = i >> 4, k = (i & 15) << 2;
                h4 hv = {(_Float16)v.x, (_Float16)v.y, (_Float16)v.z, (_Float16)v.w};
                *reinterpret_cast<h4*>(&smh[WOUTH + j * 72 + k]) = hv;
            }
            {
                float4 v = reinterpret_cast<const float4*>(mlp_w1 + li * 512)[tid];
                int j = tid >> 2, k = (tid & 3) << 2;
                h4 hv = {(_Float16)v.x, (_Float16)v.y, (_Float16)v.z, (_Float16)v.w};
                *reinterpret_cast<h4*>(&smh[WM1H + j * 24 + k]) = hv;
            }
            {
                float4 v = reinterpret_cast<const float4*>(mlp_w2 + li * 512)[tid];
                int j = tid >> 3, k = (tid & 7) << 2;
                h4 hv = {(_Float16)v.x, (_Float16)v.y, (_Float16)v.z, (_Float16)v.w};
                *reinterpret_cast<h4*>(&smh[WM2H + j * 40 + k]) = hv;
            }
            #pragma unroll
            for (int p = 0; p < 2; ++p) {
                int i = tid + p * 128;            // 256 bias slots
                if (i < 192)       smf[BQKVF + i]       = qkv_b[li * 192 + i];
                else if (i < 208)  smf[BOUTF + i - 192] = out_b[li * 16 + i - 192];
                else if (i < 240)  smf[BM1F + i - 208]  = mlp_b1[li * 32 + i - 208];
                else               smf[BM2F + i - 240]  = mlp_b2[li * 16 + i - 240];
            }
            if (tid >= 64 && tid < 80)        smf[LN1GF + tid - 64]  = ln1_g[li * 16 + tid - 64];
            else if (tid >= 80 && tid < 96)   smf[LN1BF + tid - 80]  = ln1_b[li * 16 + tid - 80];
            else if (tid >= 96 && tid < 112)  smf[LN2GF + tid - 96]  = ln2_g[li * 16 + tid - 96];
            else if (tid >= 112 && tid < 128) smf[LN2BF + tid - 112] = ln2_b[li * 16 + tid - 112];
        }
        __syncthreads();

        {
            float g = smf[LN1GF + d16], bb = smf[LN1BF + d16];
            smh[sb + SH1H + t6c * 24 + d16] = (_Float16)ln_norm16(zA, g, bb);
        }
        WAVE_SYNC();

        h8 hA0 = *reinterpret_cast<const h8*>(&smh[sb + SH1H + t6c * 24]);
        h8 hA1 = *reinterpret_cast<const h8*>(&smh[sb + SH1H + t6c * 24 + 8]);

        #pragma unroll 2
        for (int r = 0; r < 12; ++r) {
            int j = d16 + 16 * r;
            h8 w0 = *reinterpret_cast<const h8*>(&smh[WQKVH + j * 24]);
            h8 w1 = *reinterpret_cast<const h8*>(&smh[WQKVH + j * 24 + 8]);
            float bb = smf[BQKVF + j];
            smh[sb + SQKVH + t6c * 200 + j] = (_Float16)dot16h(hA0, hA1, w0, w1, bb);
        }
        __syncthreads();

        {
            bool act = (wav == 0) ? (al < 32) : (al < 16);
            if (act) {
                int h  = al & 7;
                int qs = (wav == 0) ? (al >> 3) : 4 + (al >> 3);
                const int qoff = sb + SQKVH + qs * 200 + h * 8;
                h8 qA = *reinterpret_cast<const h8*>(&smh[qoff]);
                float scA[6];
                #pragma unroll
                for (int t = 0; t < 6; ++t) {
                    h8 kA = *reinterpret_cast<const h8*>(&smh[sb + SQKVH + t * 200 + 64 + h * 8]);
                    scA[t] = dot8h(qA, kA, 0.f) * 0.35355339059327373f;
                }
                float mxA = scA[0];
                #pragma unroll
                for (int t = 1; t < 6; ++t) mxA = fmaxf(mxA, scA[t]);
                float suA = 0.f;
                #pragma unroll
                for (int t = 0; t < 6; ++t) { scA[t] = __expf(scA[t] - mxA); suA += scA[t]; }
                float ivA = 1.f / suA;
                h2 oA[4];
                #pragma unroll
                for (int k2 = 0; k2 < 4; ++k2) oA[k2] = h2{0, 0};
                #pragma unroll
                for (int t = 0; t < 6; ++t) {
                    h8 vA = *reinterpret_cast<const h8*>(&smh[sb + SQKVH + t * 200 + 128 + h * 8]);
                    _Float16 aa = (_Float16)(scA[t] * ivA);
                    h2 av = {aa, aa};
                    #pragma unroll
                    for (int k2 = 0; k2 < 4; ++k2) {
                        h2 va = {vA[2*k2], vA[2*k2+1]};
                        oA[k2] += av * va;
                    }
                }
                h8 stA;
                #pragma unroll
                for (int k2 = 0; k2 < 4; ++k2) {
                    stA[2*k2] = oA[k2][0]; stA[2*k2+1] = oA[k2][1];
                }
                *reinterpret_cast<h8*>(&smh[qoff]) = stA;
            }
        }
        WAVE_SYNC();

        {
            float aA = smf[BOUTF + d16];
            #pragma unroll
            for (int i = 0; i < 8; ++i) {
                h8 w  = *reinterpret_cast<const h8*>(&smh[WOUTH + d16 * 72 + 8 * i]);
                h8 va = *reinterpret_cast<const h8*>(&smh[sb + SQKVH + t6c * 200 + 8 * i]);
                aA = dot8h(va, w, aA);
            }
            zA += aA;
        }

        {
            float g = smf[LN2GF + d16], bb = smf[LN2BF + d16];
            smh[sb + SH1H + t6c * 24 + d16] = (_Float16)ln_norm16(zA, g, bb);
        }
        WAVE_SYNC();
        hA0 = *reinterpret_cast<const h8*>(&smh[sb + SH1H + t6c * 24]);
        hA1 = *reinterpret_cast<const h8*>(&smh[sb + SH1H + t6c * 24 + 8]);

        #pragma unroll
        for (int r = 0; r < 2; ++r) {
            int uu = d16 + 16 * r;
            h8 w0 = *reinterpret_cast<const h8*>(&smh[WM1H + uu * 24]);
            h8 w1 = *reinterpret_cast<const h8*>(&smh[WM1H + uu * 24 + 8]);
            float bb = smf[BM1F + uu];
            float aA = dot16h(hA0, hA1, w0, w1, bb);
            smh[sb + SMHSH + t6c * 40 + uu] = (_Float16)gelu_exact(aA);
        }
        WAVE_SYNC();

        {
            float aA = smf[BM2F + d16];
            #pragma unroll
            for (int i = 0; i < 4; ++i) {
                h8 w  = *reinterpret_cast<const h8*>(&smh[WM2H + d16 * 40 + 8 * i]);
                h8 va = *reinterpret_cast<const h8*>(&smh[sb + SMHSH + t6c * 40 + 8 * i]);
                aA = dot8h(va, w, aA);
            }
            zA += aA;
        }
    }

    if (tid < 16) {
        float g = head_ln_g[d16], bb = head_ln_b[d16];
        float w0 = head_w[d16], w1 = head_w[16 + d16];
        float cvA = ln_norm16(zA, g, bb);
        float pA0 = cvA * w0, pA1 = cvA * w1;
        #pragma unroll
        for (int off = 8; off >= 1; off >>= 1) {
            pA0 += __shfl_xor(pA0, off, 16);
            pA1 += __shfl_xor(pA1, off, 16);
        }
        if (tid == 0) {
            float l0 = pA0 + head_b[0], l1 = pA1 + head_b[1];
            float mx = fmaxf(l0, l1);
            float e0 = __expf(l0 - mx), e1 = __expf(l1 - mx);
            float inv = 1.f / (e0 + e1);
            out[sA * 2 + 0] = e0 * inv;
            out[sA * 2 + 1] = e1 * inv;
        }
    }
}

extern "C" void kernel_launch(void* const* d_in, const int* in_sizes, int n_in,
                              void* d_out, int out_size, void* d_ws, size_t ws_size,
                              hipStream_t stream) {
    (void)n_in; (void)ws_size; (void)out_size;
    const float* a0  = (const float*)d_in[0];   // x
    const float* a1  = (const float*)d_in[1];   // conv_t_w
    const float* a2  = (const float*)d_in[2];   // conv_t_b
    const float* a3  = (const float*)d_in[3];   // bn1_g
    const float* a4  = (const float*)d_in[4];   // bn1_b
    const float* a5  = (const float*)d_in[5];   // bn1_m
    const float* a6  = (const float*)d_in[6];   // bn1_v
    const float* a7  = (const float*)d_in[7];   // conv_s_w
    const float* a8  = (const float*)d_in[8];   // conv_s_b
    const float* a9  = (const float*)d_in[9];   // bn2_g
    const float* a10 = (const float*)d_in[10];  // bn2_b
    const float* a11 = (const float*)d_in[11];  // bn2_m
    const float* a12 = (const float*)d_in[12];  // bn2_v
    const float* a13 = (const float*)d_in[13];  // proj_w
    const float* a14 = (const float*)d_in[14];  // proj_b
    const float* a15 = (const float*)d_in[15];  // cls_token
    const float* a16 = (const float*)d_in[16];  // pe
    const float* a17 = (const float*)d_in[17];  // qkv_w
    const float* a18 = (const float*)d_in[18];  // qkv_b
    const float* a19 = (const float*)d_in[19];  // out_w
    const float* a20 = (const float*)d_in[20];  // out_b
    const float* a21 = (const float*)d_in[21];  // ln1_g
    const float* a22 = (const float*)d_in[22];  // ln1_b
    const float* a23 = (const float*)d_in[23];  // ln2_g
    const float* a24 = (const float*)d_in[24];  // ln2_b
    const float* a25 = (const float*)d_in[25];  // mlp_w1
    const float* a26 = (const float*)d_in[26];  // mlp_b1
    const float* a27 = (const float*)d_in[27];  // mlp_w2
    const float* a28 = (const float*)d_in[28];  // mlp_b2
    const float* a29 = (const float*)d_in[29];  // head_ln_g
    const float* a30 = (const float*)d_in[30];  // head_ln_b
    const float* a31 = (const float*)d_in[31];  // head_w
    const float* a32 = (const float*)d_in[32];  // head_b

    int Bn = in_sizes[0] / (64 * 125);          // 2048
    float* tokws = (float*)d_ws;                // 2048 x 80 f32 = 640 KB

    eegnet_frontend<<<Bn, 128, 0, stream>>>(
        a0, a1, a2, a3, a4, a5, a6, a7, a8, a9, a10, a11, a12, a13, a14, tokws);

    eegnet_transformer<<<Bn, 128, 0, stream>>>(
        a15, a16, a17, a18, a19, a20, a21, a22, a23, a24, a25, a26, a27, a28,
        a29, a30, a31, a32, tokws, (float*)d_out);
}

// Round 5
// 219.039 us; speedup vs baseline: 1.4749x; 1.0957x over previous
//
#include <hip/hip_runtime.h>

// Wave-synchronous fence: DS ops complete in order within a wave (ISA
// guarantee); this only stops the COMPILER from reordering/caching LDS.
#define WAVE_SYNC() do { asm volatile("" ::: "memory"); \
                         __builtin_amdgcn_wave_barrier(); \
                         asm volatile("" ::: "memory"); } while (0)

typedef _Float16 h2 __attribute__((ext_vector_type(2)));
typedef _Float16 h4 __attribute__((ext_vector_type(4)));
typedef _Float16 h8 __attribute__((ext_vector_type(8)));

__device__ __forceinline__ float fdot2(h2 a, h2 b, float c) {
#if defined(__has_builtin)
#if __has_builtin(__builtin_amdgcn_fdot2)
    return __builtin_amdgcn_fdot2(a, b, c, false);
#else
    return (float)a[0]*(float)b[0] + (float)a[1]*(float)b[1] + c;
#endif
#else
    return (float)a[0]*(float)b[0] + (float)a[1]*(float)b[1] + c;
#endif
}

__device__ __forceinline__ float dot8h(h8 a, h8 b, float c) {
    float s = c;
    #pragma unroll
    for (int i = 0; i < 4; ++i) {
        h2 x = {a[2*i], a[2*i+1]};
        h2 y = {b[2*i], b[2*i+1]};
        s = fdot2(x, y, s);
    }
    return s;
}

__device__ __forceinline__ float dot16h(h8 a0, h8 a1, h8 b0, h8 b1, float c) {
    return dot8h(a1, b1, dot8h(a0, b0, c));
}

__device__ __forceinline__ float ln_norm16(float z, float g, float bb) {
    float s = z, q = z * z;
    #pragma unroll
    for (int off = 8; off >= 1; off >>= 1) {
        s += __shfl_xor(s, off, 16);
        q += __shfl_xor(q, off, 16);
    }
    float mean = s * 0.0625f;
    float var  = q * 0.0625f - mean * mean;
    return (z - mean) * rsqrtf(var + 1e-5f) * g + bb;
}

__device__ __forceinline__ float gelu_exact(float a) {
    float xa = fabsf(a) * 0.70710678118654752f;
    float tt = 1.f / (1.f + 0.3275911f * xa);
    float poly = tt * (0.254829592f + tt * (-0.284496736f + tt * (1.421413741f
               + tt * (-1.453152027f + tt * 1.061405429f))));
    float erfv = 1.f - poly * __expf(-xa * xa);
    erfv = a >= 0.f ? erfv : -erfv;
    return 0.5f * a * (1.f + erfv);
}

// ========================= FUSED kernel ======================================
// v6: frontend + transformer in ONE kernel. Rationale: R0 wall (217us) !=
// frontend dispatch (72) + transformer dispatch (<64) -- ~80us sits in the
// inter-kernel drain/launch/fill bubble. Dependency is 1:1 per sample
// (frontend block b -> tok[b] -> transformer of sample b), so fusing with the
// same partition is legal. Block = 128 thr = 2 samples, grid 1024.
//   Phase A: R0's proven 64-thr frontend, one WAVE per sample (per-wave LDS
//            region, WAVE_SYNC only). tok -> LDS (no global roundtrip).
//   Phase B: R0's proven dual-sample (zA/zB) transformer compute with the
//            128-thr staging loops.
// LDS: 2 x 4448 f32 (phase A) + 160 f32 tok = 36224 B -> 4 blocks/CU
//      (= 8 waves/CU, same occupancy both R0 kernels ran at).
// Phase-B arena (21952 B) overlays phase-A regions (dead after boundary);
// tok at byte 35584 is above everything phase B touches.

// ---- phase A layout (per-wave, floats) ----
#define F_XSTR 204         // XSP row stride (f32)
#define F_PL   4000        // pool region (f32 idx, above XR's 16000 B)
#define F_TOT  4448        // per-wave floats (17792 B)
#define TOKF   8896        // tok region: 2 x 80 f32
#define FUSED_TOTF 9056    // 36224 B total

// ---- phase B arena (same offsets as R0 transformer, 2 scratch strips) ----
#define WQKVH 0          // 192 rows, stride 24 halfs
#define WOUTH 4608       // 16 rows, stride 72
#define WM1H  5760       // 32 rows, stride 24
#define WM2H  6528       // 16 rows, stride 40
#define BQKVF 3584       // float idx
#define BOUTF 3776
#define BM1F  3792
#define BM2F  3824
#define LN1GF 3840
#define LN1BF 3856
#define LN2GF 3872
#define LN2BF 3888
#define SCR0  7808       // half idx
#define SSTRH 1584
#define SH1H  0
#define SQKVH 144
#define SMHSH 1344

extern "C" __global__ __launch_bounds__(128, 2)
void eegnet_fused(
    const float* __restrict__ x,
    const float* __restrict__ conv_t_w, const float* __restrict__ conv_t_b,
    const float* __restrict__ bn1_g, const float* __restrict__ bn1_b,
    const float* __restrict__ bn1_m, const float* __restrict__ bn1_v,
    const float* __restrict__ conv_s_w, const float* __restrict__ conv_s_b,
    const float* __restrict__ bn2_g, const float* __restrict__ bn2_b,
    const float* __restrict__ bn2_m, const float* __restrict__ bn2_v,
    const float* __restrict__ proj_w, const float* __restrict__ proj_b,
    const float* __restrict__ cls_token, const float* __restrict__ pe,
    const float* __restrict__ qkv_w, const float* __restrict__ qkv_b,
    const float* __restrict__ out_w, const float* __restrict__ out_b,
    const float* __restrict__ ln1_g, const float* __restrict__ ln1_b,
    const float* __restrict__ ln2_g, const float* __restrict__ ln2_b,
    const float* __restrict__ mlp_w1, const float* __restrict__ mlp_b1,
    const float* __restrict__ mlp_w2, const float* __restrict__ mlp_b2,
    const float* __restrict__ head_ln_g, const float* __restrict__ head_ln_b,
    const float* __restrict__ head_w, const float* __restrict__ head_b,
    float* __restrict__ out)
{
    __shared__ __align__(16) float sm[FUSED_TOTF];
    _Float16* smh = reinterpret_cast<_Float16*>(sm);

    const int tid  = threadIdx.x;
    const int lane = tid & 63;
    const int w    = tid >> 6;
    const int b    = blockIdx.x * 2 + w;      // phase-A sample of this wave

    // ======================= PHASE A: conv frontend ==========================
    {
        float* smw = sm + w * F_TOT;
        _Float16* xr = reinterpret_cast<_Float16*>(smw);

        // ---- stage 0: x -> LDS as f16 (linear ring, coalesced float4) ----
        {
            const float4* xb4 = reinterpret_cast<const float4*>(x + (size_t)b * 8000);
            #pragma unroll
            for (int k = 0; k < 32; ++k) {
                int g = min(k * 64 + lane, 1999);   // tail lanes dup (same value)
                float4 v = xb4[g];
                h4 hv = {(_Float16)v.x, (_Float16)v.y, (_Float16)v.z, (_Float16)v.w};
                *reinterpret_cast<h4*>(&xr[4 * g]) = hv;
            }
        }
        WAVE_SYNC();   // XR writes -> XR reads (same wave, DS in-order)

        // ---- stage 1: spatial conv from XR columns; write XSP (aliases XR) --
        {
            const int l2 = min(lane, 60);
            float a0[16], a1[16];
            #pragma unroll
            for (int o = 0; o < 16; ++o) { a0[o] = 0.f; a1[o] = 0.f; }
            #pragma unroll 8
            for (int c = 0; c < 64; ++c) {
                float xv0 = (float)xr[c * 125 + lane];
                float xv1 = (float)xr[c * 125 + 64 + l2];
                #pragma unroll
                for (int o = 0; o < 16; ++o) {
                    float wv = conv_s_w[o * 64 + c];     // wave-uniform -> s_load
                    a0[o] += wv * xv0;
                    a1[o] += wv * xv1;
                }
            }
            WAVE_SYNC();   // all XR reads retired before aliased XSP writes

            for (int i = lane; i < 16 * 79; i += 64) {
                int row = i / 79, k = i - row * 79;
                int off = (k < 32) ? k : (k + 125);
                smw[row * F_XSTR + off] = 0.f;
            }
            #pragma unroll
            for (int o = 0; o < 16; ++o) {
                smw[o * F_XSTR + 32 + lane] = a0[o];
                if (lane < 61) smw[o * F_XSTR + 96 + lane] = a1[o];
            }
        }

        // ---- fused BN constants + temporal taps ----
        const int oo = lane & 15, qg4 = lane >> 4, gg = oo >> 1;
        float sa, cc;
        {
            float s1 = bn1_g[gg] * rsqrtf(bn1_v[gg] + 1e-5f);
            float b1 = (conv_t_b[gg] - bn1_m[gg]) * s1 + bn1_b[gg];
            float s2 = bn2_g[oo] * rsqrtf(bn2_v[oo] + 1e-5f);
            float ssum = 0.f;
            const float4* csw = reinterpret_cast<const float4*>(conv_s_w + oo * 64);
            #pragma unroll
            for (int i = 0; i < 16; ++i) {
                float4 v = csw[i];
                ssum += v.x + v.y + v.z + v.w;
            }
            sa = s1 * s2;
            cc = (b1 * ssum + conv_s_b[oo] - bn2_m[oo]) * s2 + bn2_b[oo];
        }
        float wt[63];
        #pragma unroll
        for (int k = 0; k < 63; ++k) wt[k] = conv_t_w[gg * 63 + k];

        WAVE_SYNC();

        // ---- stage 2: temporal conv + BN + ELU + avg-pool ----
        #pragma unroll 2
        for (int jj = 0; jj < 7; ++jj) {
            int j  = qg4 * 7 + jj;
            int jc = min(j, 24);
            int base = oo * F_XSTR + 5 * jc + 1;
            float acc5[5] = {0.f, 0.f, 0.f, 0.f, 0.f};
            #pragma unroll
            for (int m = 0; m < 67; ++m) {
                float xv = smw[base + m];
                #pragma unroll
                for (int u = 0; u < 5; ++u)
                    if (u <= m && m - u <= 62) acc5[u] += wt[m - u] * xv;
            }
            float psum = 0.f;
            #pragma unroll
            for (int u = 0; u < 5; ++u) {
                float v = acc5[u] * sa + cc;
                psum += (v > 0.f) ? v : (__expf(v) - 1.f);
            }
            if (j == jc) smw[F_PL + oo * 28 + j] = psum * 0.2f;
        }

        WAVE_SYNC();

        // ---- stage 3: token projection -> LDS tok (no global roundtrip) ----
        #pragma unroll
        for (int pass = 0; pass < 2; ++pass) {
            int oi = (pass == 0) ? lane : (64 + lane);
            int p = oi >> 4, dd = oi & 15;
            int pc = min(p, 4);
            bool act = (pass == 0) || (lane < 16);
            float acc = proj_b[dd];
            const float4* wp = reinterpret_cast<const float4*>(proj_w + dd * 80);
            #pragma unroll
            for (int i = 0; i < 20; ++i) {
                float4 w4 = wp[i];
                acc += w4.x * smw[F_PL + ((4*i+0)/5) * 28 + pc * 5 + ((4*i+0)%5)];
                acc += w4.y * smw[F_PL + ((4*i+1)/5) * 28 + pc * 5 + ((4*i+1)%5)];
                acc += w4.z * smw[F_PL + ((4*i+2)/5) * 28 + pc * 5 + ((4*i+2)%5)];
                acc += w4.w * smw[F_PL + ((4*i+3)/5) * 28 + pc * 5 + ((4*i+3)%5)];
            }
            if (act) sm[TOKF + w * 80 + pc * 16 + dd] = acc;
        }
    }

    __syncthreads();   // phase boundary: both waves' tok ready

    // ======================= PHASE B: transformer + head =====================
    const int d16 = tid & 15, qg = tid >> 4;
    const int t6c = min(qg, 5);
    const int wav = tid >> 6, al = tid & 63;
    const int sbA = SCR0;
    const int sbB = SCR0 + SSTRH;
    const int sA  = blockIdx.x * 2;

    float zA, zB;
    {
        float peV = pe[t6c * 16 + d16];
        if (t6c == 0) {
            float cv = cls_token[d16];
            zA = cv + peV; zB = cv + peV;
        } else {
            zA = sm[TOKF +      (t6c - 1) * 16 + d16] + peV;
            zB = sm[TOKF + 80 + (t6c - 1) * 16 + d16] + peV;
        }
    }

    #pragma unroll 1
    for (int li = 0; li < 6; ++li) {
        __syncthreads();

        {
            const float4* s1 = reinterpret_cast<const float4*>(qkv_w + li * 3072);
            #pragma unroll
            for (int it = 0; it < 6; ++it) {
                int i = tid + it * 128;           // 768 float4
                float4 v = s1[i];
                int j = i >> 2, k = (i & 3) << 2;
                h4 hv = {(_Float16)v.x, (_Float16)v.y, (_Float16)v.z, (_Float16)v.w};
                *reinterpret_cast<h4*>(&smh[WQKVH + j * 24 + k]) = hv;
            }
            const float4* s2 = reinterpret_cast<const float4*>(out_w + li * 1024);
            #pragma unroll
            for (int it = 0; it < 2; ++it) {
                int i = tid + it * 128;           // 256 float4
                float4 v = s2[i];
                int j = i >> 4, k = (i & 15) << 2;
                h4 hv = {(_Float16)v.x, (_Float16)v.y, (_Float16)v.z, (_Float16)v.w};
                *reinterpret_cast<h4*>(&smh[WOUTH + j * 72 + k]) = hv;
            }
            {
                float4 v = reinterpret_cast<const float4*>(mlp_w1 + li * 512)[tid];
                int j = tid >> 2, k = (tid & 3) << 2;
                h4 hv = {(_Float16)v.x, (_Float16)v.y, (_Float16)v.z, (_Float16)v.w};
                *reinterpret_cast<h4*>(&smh[WM1H + j * 24 + k]) = hv;
            }
            {
                float4 v = reinterpret_cast<const float4*>(mlp_w2 + li * 512)[tid];
                int j = tid >> 3, k = (tid & 7) << 2;
                h4 hv = {(_Float16)v.x, (_Float16)v.y, (_Float16)v.z, (_Float16)v.w};
                *reinterpret_cast<h4*>(&smh[WM2H + j * 40 + k]) = hv;
            }
            #pragma unroll
            for (int p = 0; p < 2; ++p) {
                int i = tid + p * 128;            // 256 bias slots
                if (i < 192)       sm[BQKVF + i]       = qkv_b[li * 192 + i];
                else if (i < 208)  sm[BOUTF + i - 192] = out_b[li * 16 + i - 192];
                else if (i < 240)  sm[BM1F + i - 208]  = mlp_b1[li * 32 + i - 208];
                else               sm[BM2F + i - 240]  = mlp_b2[li * 16 + i - 240];
            }
            if (tid >= 64 && tid < 80)        sm[LN1GF + tid - 64]  = ln1_g[li * 16 + tid - 64];
            else if (tid >= 80 && tid < 96)   sm[LN1BF + tid - 80]  = ln1_b[li * 16 + tid - 80];
            else if (tid >= 96 && tid < 112)  sm[LN2GF + tid - 96]  = ln2_g[li * 16 + tid - 96];
            else if (tid >= 112 && tid < 128) sm[LN2BF + tid - 112] = ln2_b[li * 16 + tid - 112];
        }
        __syncthreads();

        {
            float g = sm[LN1GF + d16], bb = sm[LN1BF + d16];
            smh[sbA + SH1H + t6c * 24 + d16] = (_Float16)ln_norm16(zA, g, bb);
            smh[sbB + SH1H + t6c * 24 + d16] = (_Float16)ln_norm16(zB, g, bb);
        }
        WAVE_SYNC();

        h8 hA0 = *reinterpret_cast<const h8*>(&smh[sbA + SH1H + t6c * 24]);
        h8 hA1 = *reinterpret_cast<const h8*>(&smh[sbA + SH1H + t6c * 24 + 8]);
        h8 hB0 = *reinterpret_cast<const h8*>(&smh[sbB + SH1H + t6c * 24]);
        h8 hB1 = *reinterpret_cast<const h8*>(&smh[sbB + SH1H + t6c * 24 + 8]);

        #pragma unroll 2
        for (int r = 0; r < 12; ++r) {
            int j = d16 + 16 * r;
            h8 w0 = *reinterpret_cast<const h8*>(&smh[WQKVH + j * 24]);
            h8 w1 = *reinterpret_cast<const h8*>(&smh[WQKVH + j * 24 + 8]);
            float bb = sm[BQKVF + j];
            smh[sbA + SQKVH + t6c * 200 + j] = (_Float16)dot16h(hA0, hA1, w0, w1, bb);
            smh[sbB + SQKVH + t6c * 200 + j] = (_Float16)dot16h(hB0, hB1, w0, w1, bb);
        }
        __syncthreads();

        {
            bool act = (wav == 0) ? (al < 32) : (al < 16);
            if (act) {
                int h  = al & 7;
                int qs = (wav == 0) ? (al >> 3) : 4 + (al >> 3);
                const int qoffA = sbA + SQKVH + qs * 200 + h * 8;
                const int qoffB = sbB + SQKVH + qs * 200 + h * 8;
                h8 qA = *reinterpret_cast<const h8*>(&smh[qoffA]);
                h8 qB = *reinterpret_cast<const h8*>(&smh[qoffB]);
                float scA[6], scB[6];
                #pragma unroll
                for (int t = 0; t < 6; ++t) {
                    h8 kA = *reinterpret_cast<const h8*>(&smh[sbA + SQKVH + t * 200 + 64 + h * 8]);
                    h8 kB = *reinterpret_cast<const h8*>(&smh[sbB + SQKVH + t * 200 + 64 + h * 8]);
                    scA[t] = dot8h(qA, kA, 0.f) * 0.35355339059327373f;
                    scB[t] = dot8h(qB, kB, 0.f) * 0.35355339059327373f;
                }
                float mxA = scA[0], mxB = scB[0];
                #pragma unroll
                for (int t = 1; t < 6; ++t) { mxA = fmaxf(mxA, scA[t]); mxB = fmaxf(mxB, scB[t]); }
                float suA = 0.f, suB = 0.f;
                #pragma unroll
                for (int t = 0; t < 6; ++t) {
                    scA[t] = __expf(scA[t] - mxA); suA += scA[t];
                    scB[t] = __expf(scB[t] - mxB); suB += scB[t];
                }
                float ivA = 1.f / suA, ivB = 1.f / suB;
                h2 oA[4], oB[4];
                #pragma unroll
                for (int k2 = 0; k2 < 4; ++k2) { oA[k2] = h2{0, 0}; oB[k2] = h2{0, 0}; }
                #pragma unroll
                for (int t = 0; t < 6; ++t) {
                    h8 vA = *reinterpret_cast<const h8*>(&smh[sbA + SQKVH + t * 200 + 128 + h * 8]);
                    h8 vB = *reinterpret_cast<const h8*>(&smh[sbB + SQKVH + t * 200 + 128 + h * 8]);
                    _Float16 aa = (_Float16)(scA[t] * ivA);
                    _Float16 ab = (_Float16)(scB[t] * ivB);
                    h2 av = {aa, aa}, bv = {ab, ab};
                    #pragma unroll
                    for (int k2 = 0; k2 < 4; ++k2) {
                        h2 va = {vA[2*k2], vA[2*k2+1]};
                        h2 vb = {vB[2*k2], vB[2*k2+1]};
                        oA[k2] += av * va;
                        oB[k2] += bv * vb;
                    }
                }
                h8 stA, stB;
                #pragma unroll
                for (int k2 = 0; k2 < 4; ++k2) {
                    stA[2*k2] = oA[k2][0]; stA[2*k2+1] = oA[k2][1];
                    stB[2*k2] = oB[k2][0]; stB[2*k2+1] = oB[k2][1];
                }
                *reinterpret_cast<h8*>(&smh[qoffA]) = stA;
                *reinterpret_cast<h8*>(&smh[qoffB]) = stB;
            }
        }
        WAVE_SYNC();

        {
            float aA = sm[BOUTF + d16], aB = aA;
            #pragma unroll
            for (int i = 0; i < 8; ++i) {
                h8 wv = *reinterpret_cast<const h8*>(&smh[WOUTH + d16 * 72 + 8 * i]);
                h8 va = *reinterpret_cast<const h8*>(&smh[sbA + SQKVH + t6c * 200 + 8 * i]);
                h8 vb = *reinterpret_cast<const h8*>(&smh[sbB + SQKVH + t6c * 200 + 8 * i]);
                aA = dot8h(va, wv, aA);
                aB = dot8h(vb, wv, aB);
            }
            zA += aA; zB += aB;
        }

        {
            float g = sm[LN2GF + d16], bb = sm[LN2BF + d16];
            smh[sbA + SH1H + t6c * 24 + d16] = (_Float16)ln_norm16(zA, g, bb);
            smh[sbB + SH1H + t6c * 24 + d16] = (_Float16)ln_norm16(zB, g, bb);
        }
        WAVE_SYNC();
        hA0 = *reinterpret_cast<const h8*>(&smh[sbA + SH1H + t6c * 24]);
        hA1 = *reinterpret_cast<const h8*>(&smh[sbA + SH1H + t6c * 24 + 8]);
        hB0 = *reinterpret_cast<const h8*>(&smh[sbB + SH1H + t6c * 24]);
        hB1 = *reinterpret_cast<const h8*>(&smh[sbB + SH1H + t6c * 24 + 8]);

        #pragma unroll
        for (int r = 0; r < 2; ++r) {
            int uu = d16 + 16 * r;
            h8 w0 = *reinterpret_cast<const h8*>(&smh[WM1H + uu * 24]);
            h8 w1 = *reinterpret_cast<const h8*>(&smh[WM1H + uu * 24 + 8]);
            float bb = sm[BM1F + uu];
            float aA = dot16h(hA0, hA1, w0, w1, bb);
            float aB = dot16h(hB0, hB1, w0, w1, bb);
            smh[sbA + SMHSH + t6c * 40 + uu] = (_Float16)gelu_exact(aA);
            smh[sbB + SMHSH + t6c * 40 + uu] = (_Float16)gelu_exact(aB);
        }
        WAVE_SYNC();

        {
            float aA = sm[BM2F + d16], aB = aA;
            #pragma unroll
            for (int i = 0; i < 4; ++i) {
                h8 wv = *reinterpret_cast<const h8*>(&smh[WM2H + d16 * 40 + 8 * i]);
                h8 va = *reinterpret_cast<const h8*>(&smh[sbA + SMHSH + t6c * 40 + 8 * i]);
                h8 vb = *reinterpret_cast<const h8*>(&smh[sbB + SMHSH + t6c * 40 + 8 * i]);
                aA = dot8h(va, wv, aA);
                aB = dot8h(vb, wv, aB);
            }
            zA += aA; zB += aB;
        }
    }

    if (tid < 16) {
        float g = head_ln_g[d16], bb = head_ln_b[d16];
        float w0 = head_w[d16], w1 = head_w[16 + d16];
        float cvA = ln_norm16(zA, g, bb);
        float cvB = ln_norm16(zB, g, bb);
        float pA0 = cvA * w0, pA1 = cvA * w1;
        float pB0 = cvB * w0, pB1 = cvB * w1;
        #pragma unroll
        for (int off = 8; off >= 1; off >>= 1) {
            pA0 += __shfl_xor(pA0, off, 16);
            pA1 += __shfl_xor(pA1, off, 16);
            pB0 += __shfl_xor(pB0, off, 16);
            pB1 += __shfl_xor(pB1, off, 16);
        }
        if (tid == 0) {
            float hb0 = head_b[0], hb1 = head_b[1];
            {
                float l0 = pA0 + hb0, l1 = pA1 + hb1;
                float mx = fmaxf(l0, l1);
                float e0 = __expf(l0 - mx), e1 = __expf(l1 - mx);
                float inv = 1.f / (e0 + e1);
                out[sA * 2 + 0] = e0 * inv;
                out[sA * 2 + 1] = e1 * inv;
            }
            {
                float l0 = pB0 + hb0, l1 = pB1 + hb1;
                float mx = fmaxf(l0, l1);
                float e0 = __expf(l0 - mx), e1 = __expf(l1 - mx);
                float inv = 1.f / (e0 + e1);
                out[(sA + 1) * 2 + 0] = e0 * inv;
                out[(sA + 1) * 2 + 1] = e1 * inv;
            }
        }
    }
}

extern "C" void kernel_launch(void* const* d_in, const int* in_sizes, int n_in,
                              void* d_out, int out_size, void* d_ws, size_t ws_size,
                              hipStream_t stream) {
    (void)n_in; (void)ws_size; (void)out_size; (void)d_ws;
    const float* a0  = (const float*)d_in[0];   // x
    const float* a1  = (const float*)d_in[1];   // conv_t_w
    const float* a2  = (const float*)d_in[2];   // conv_t_b
    const float* a3  = (const float*)d_in[3];   // bn1_g
    const float* a4  = (const float*)d_in[4];   // bn1_b
    const float* a5  = (const float*)d_in[5];   // bn1_m
    const float* a6  = (const float*)d_in[6];   // bn1_v
    const float* a7  = (const float*)d_in[7];   // conv_s_w
    const float* a8  = (const float*)d_in[8];   // conv_s_b
    const float* a9  = (const float*)d_in[9];   // bn2_g
    const float* a10 = (const float*)d_in[10];  // bn2_b
    const float* a11 = (const float*)d_in[11];  // bn2_m
    const float* a12 = (const float*)d_in[12];  // bn2_v
    const float* a13 = (const float*)d_in[13];  // proj_w
    const float* a14 = (const float*)d_in[14];  // proj_b
    const float* a15 = (const float*)d_in[15];  // cls_token
    const float* a16 = (const float*)d_in[16];  // pe
    const float* a17 = (const float*)d_in[17];  // qkv_w
    const float* a18 = (const float*)d_in[18];  // qkv_b
    const float* a19 = (const float*)d_in[19];  // out_w
    const float* a20 = (const float*)d_in[20];  // out_b
    const float* a21 = (const float*)d_in[21];  // ln1_g
    const float* a22 = (const float*)d_in[22];  // ln1_b
    const float* a23 = (const float*)d_in[23];  // ln2_g
    const float* a24 = (const float*)d_in[24];  // ln2_b
    const float* a25 = (const float*)d_in[25];  // mlp_w1
    const float* a26 = (const float*)d_in[26];  // mlp_b1
    const float* a27 = (const float*)d_in[27];  // mlp_w2
    const float* a28 = (const float*)d_in[28];  // mlp_b2
    const float* a29 = (const float*)d_in[29];  // head_ln_g
    const float* a30 = (const float*)d_in[30];  // head_ln_b
    const float* a31 = (const float*)d_in[31];  // head_w
    const float* a32 = (const float*)d_in[32];  // head_b

    int Bn = in_sizes[0] / (64 * 125);          // 2048

    eegnet_fused<<<Bn / 2, 128, 0, stream>>>(
        a0, a1, a2, a3, a4, a5, a6, a7, a8, a9, a10, a11, a12,
        a13, a14, a15, a16, a17, a18, a19, a20, a21, a22, a23, a24,
        a25, a26, a27, a28, a29, a30, a31, a32, (float*)d_out);
}